// Round 4
// baseline (1089.165 us; speedup 1.0000x reference)
//
#include <hip/hip_runtime.h>
#include <hip/hip_bf16.h>

#define N_NODES 50000
#define N_EDGES 800000
#define DIN 256
#define HID 64
#define NH 4
#define NC 40

// ---------------- CSR build ----------------

__global__ void k_hist(const int* __restrict__ dst, int* __restrict__ cnt, int E) {
    int i = blockIdx.x * blockDim.x + threadIdx.x;
    if (i < E) atomicAdd(&cnt[dst[i]], 1);
}

__global__ __launch_bounds__(1024) void k_scan(const int* __restrict__ cnt,
                                               int* __restrict__ rowptr,
                                               int* __restrict__ cursor, int Nn) {
    __shared__ int lds[1024];
    int tid = threadIdx.x;
    const int CH = (Nn + 1023) / 1024;
    int base = tid * CH;
    int s = 0;
    for (int j = 0; j < CH; ++j) {
        int idx = base + j;
        if (idx < Nn) s += cnt[idx];
    }
    lds[tid] = s;
    __syncthreads();
    for (int off = 1; off < 1024; off <<= 1) {
        int v = (tid >= off) ? lds[tid - off] : 0;
        __syncthreads();
        lds[tid] += v;
        __syncthreads();
    }
    int run = (tid == 0) ? 0 : lds[tid - 1];
    for (int j = 0; j < CH; ++j) {
        int idx = base + j;
        if (idx < Nn) {
            rowptr[idx] = run;
            cursor[idx] = run;
            run += cnt[idx];
        }
    }
    if (tid == 1023) rowptr[Nn] = lds[1023];
}

__global__ void k_fill(const int* __restrict__ src, const int* __restrict__ dst,
                       int* __restrict__ cursor, int* __restrict__ col, int E) {
    int i = blockIdx.x * blockDim.x + threadIdx.x;
    if (i < E) {
        int p = atomicAdd(&cursor[dst[i]], 1);
        col[p] = src[i];
    }
}

// ---------------- fp32 GEMM: C[M,N] = A[M,K] @ B[K,N], row-major ----------------
// BM=BN=128, BK=16, 256 threads (16x16), 8x8 per thread in split-quadrant form.
// Requires K % 16 == 0 (true here: K=256 always).

__global__ __launch_bounds__(256) void gemm_f32(const float* __restrict__ A,
                                                const float* __restrict__ B,
                                                float* __restrict__ C,
                                                int M, int N, int K) {
    __shared__ float As[16][128];  // [k][m]
    __shared__ float Bs[16][128];  // [k][n]
    const int tid = threadIdx.x;
    const int tx = tid & 15, ty = tid >> 4;
    const int bm = blockIdx.y * 128;
    const int bn = blockIdx.x * 128;

    const int a_row = tid >> 1;        // 0..127
    const int a_k = (tid & 1) * 8;     // 0 or 8
    const int b_row = tid >> 5;        // 0..7 (+8 on iter 1)
    const int b_col = (tid & 31) * 4;  // 0..124

    float acc[8][8] = {};

    for (int k0 = 0; k0 < K; k0 += 16) {
        {
            int gr = bm + a_row;
            float4 v0 = make_float4(0.f, 0.f, 0.f, 0.f);
            float4 v1 = make_float4(0.f, 0.f, 0.f, 0.f);
            if (gr < M) {
                const float4* p = (const float4*)(A + (size_t)gr * K + k0 + a_k);
                v0 = p[0];
                v1 = p[1];
            }
            As[a_k + 0][a_row] = v0.x;
            As[a_k + 1][a_row] = v0.y;
            As[a_k + 2][a_row] = v0.z;
            As[a_k + 3][a_row] = v0.w;
            As[a_k + 4][a_row] = v1.x;
            As[a_k + 5][a_row] = v1.y;
            As[a_k + 6][a_row] = v1.z;
            As[a_k + 7][a_row] = v1.w;
        }
#pragma unroll
        for (int it = 0; it < 2; ++it) {
            int kr = b_row + it * 8;
            float4 v = make_float4(0.f, 0.f, 0.f, 0.f);
            if (bn + b_col < N) v = *(const float4*)(B + (size_t)(k0 + kr) * N + bn + b_col);
            *(float4*)&Bs[kr][b_col] = v;
        }
        __syncthreads();

#pragma unroll
        for (int kk = 0; kk < 16; ++kk) {
            float a[8], b[8];
            *(float4*)&a[0] = *(const float4*)&As[kk][ty * 4];
            *(float4*)&a[4] = *(const float4*)&As[kk][64 + ty * 4];
            *(float4*)&b[0] = *(const float4*)&Bs[kk][tx * 4];
            *(float4*)&b[4] = *(const float4*)&Bs[kk][64 + tx * 4];
#pragma unroll
            for (int i = 0; i < 8; ++i)
#pragma unroll
                for (int j = 0; j < 8; ++j) acc[i][j] += a[i] * b[j];
        }
        __syncthreads();
    }

#pragma unroll
    for (int qi = 0; qi < 2; ++qi) {
#pragma unroll
        for (int i = 0; i < 4; ++i) {
            int row = bm + qi * 64 + ty * 4 + i;
            if (row >= M) continue;
#pragma unroll
            for (int qj = 0; qj < 2; ++qj) {
                int cc = bn + qj * 64 + tx * 4;
                if (cc + 3 < N) {
                    float4 v = make_float4(acc[qi * 4 + i][qj * 4 + 0],
                                           acc[qi * 4 + i][qj * 4 + 1],
                                           acc[qi * 4 + i][qj * 4 + 2],
                                           acc[qi * 4 + i][qj * 4 + 3]);
                    *(float4*)(C + (size_t)row * N + cc) = v;
                } else {
#pragma unroll
                    for (int j = 0; j < 4; ++j)
                        if (cc + j < N) C[(size_t)row * N + cc + j] = acc[qi * 4 + i][qj * 4 + j];
                }
            }
        }
    }
}

// ---------------- dual-B fp32 GEMM (layer 2): C0 = A@B0, C1 = A@B1 ----------------
// BM=128, BN=64 per output, BK=16, 256 threads, 8x4 microtile per output.
// A staged once; both outputs share it. Requires K % 16 == 0.

__global__ __launch_bounds__(256) void gemm_f32_dual(const float* __restrict__ A,
                                                     const float* __restrict__ B0,
                                                     const float* __restrict__ B1,
                                                     float* __restrict__ C0,
                                                     float* __restrict__ C1,
                                                     int M, int N, int K) {
    __shared__ float As[16][128];  // [k][m]
    __shared__ float Bs0[16][64];  // [k][n]
    __shared__ float Bs1[16][64];
    const int tid = threadIdx.x;
    const int tx = tid & 15, ty = tid >> 4;
    const int bm = blockIdx.y * 128;
    const int bn = blockIdx.x * 64;

    const int a_row = tid >> 1;        // 0..127
    const int a_k = (tid & 1) * 8;     // 0 or 8
    const int b_row = tid >> 4;        // 0..15 (all 16 k-rows)
    const int b_col = (tid & 15) * 4;  // 0..60

    float acc0[8][4] = {};
    float acc1[8][4] = {};

    for (int k0 = 0; k0 < K; k0 += 16) {
        {
            int gr = bm + a_row;
            float4 v0 = make_float4(0.f, 0.f, 0.f, 0.f);
            float4 v1 = make_float4(0.f, 0.f, 0.f, 0.f);
            if (gr < M) {
                const float4* p = (const float4*)(A + (size_t)gr * K + k0 + a_k);
                v0 = p[0];
                v1 = p[1];
            }
            As[a_k + 0][a_row] = v0.x;
            As[a_k + 1][a_row] = v0.y;
            As[a_k + 2][a_row] = v0.z;
            As[a_k + 3][a_row] = v0.w;
            As[a_k + 4][a_row] = v1.x;
            As[a_k + 5][a_row] = v1.y;
            As[a_k + 6][a_row] = v1.z;
            As[a_k + 7][a_row] = v1.w;
        }
        {
            bool ok = (bn + b_col) < N;
            float4 v0 = make_float4(0.f, 0.f, 0.f, 0.f);
            float4 v1 = make_float4(0.f, 0.f, 0.f, 0.f);
            if (ok) {
                v0 = *(const float4*)(B0 + (size_t)(k0 + b_row) * N + bn + b_col);
                v1 = *(const float4*)(B1 + (size_t)(k0 + b_row) * N + bn + b_col);
            }
            *(float4*)&Bs0[b_row][b_col] = v0;
            *(float4*)&Bs1[b_row][b_col] = v1;
        }
        __syncthreads();

#pragma unroll
        for (int kk = 0; kk < 16; ++kk) {
            float a[8], b0[4], b1[4];
            *(float4*)&a[0] = *(const float4*)&As[kk][ty * 4];
            *(float4*)&a[4] = *(const float4*)&As[kk][64 + ty * 4];
            *(float4*)&b0[0] = *(const float4*)&Bs0[kk][tx * 4];
            *(float4*)&b1[0] = *(const float4*)&Bs1[kk][tx * 4];
#pragma unroll
            for (int i = 0; i < 8; ++i)
#pragma unroll
                for (int j = 0; j < 4; ++j) {
                    acc0[i][j] += a[i] * b0[j];
                    acc1[i][j] += a[i] * b1[j];
                }
        }
        __syncthreads();
    }

#pragma unroll
    for (int qi = 0; qi < 2; ++qi) {
#pragma unroll
        for (int i = 0; i < 4; ++i) {
            int row = bm + qi * 64 + ty * 4 + i;
            if (row >= M) continue;
            int cc = bn + tx * 4;
            if (cc + 3 < N) {
                float4 v0 = make_float4(acc0[qi * 4 + i][0], acc0[qi * 4 + i][1],
                                        acc0[qi * 4 + i][2], acc0[qi * 4 + i][3]);
                float4 v1 = make_float4(acc1[qi * 4 + i][0], acc1[qi * 4 + i][1],
                                        acc1[qi * 4 + i][2], acc1[qi * 4 + i][3]);
                *(float4*)(C0 + (size_t)row * N + cc) = v0;
                *(float4*)(C1 + (size_t)row * N + cc) = v1;
            } else {
#pragma unroll
                for (int j = 0; j < 4; ++j)
                    if (cc + j < N) {
                        C0[(size_t)row * N + cc + j] = acc0[qi * 4 + i][j];
                        C1[(size_t)row * N + cc + j] = acc1[qi * 4 + i][j];
                    }
            }
        }
    }
}

// ---------------- el/er projections ----------------
__global__ __launch_bounds__(256) void elr64(const float* __restrict__ feat,
                                             const float* __restrict__ al,
                                             const float* __restrict__ ar,
                                             float* __restrict__ el,
                                             float* __restrict__ er, int Nn) {
    int wave = threadIdx.x >> 6, lane = threadIdx.x & 63;
    int n = blockIdx.x * 4 + wave;
    if (n >= Nn) return;
    const float* f = feat + (size_t)n * 256;
#pragma unroll
    for (int h = 0; h < 4; ++h) {
        float v = f[h * 64 + lane];
        float sl = v * al[h * 64 + lane];
        float sr = v * ar[h * 64 + lane];
#pragma unroll
        for (int off = 32; off; off >>= 1) {
            sl += __shfl_down(sl, off);
            sr += __shfl_down(sr, off);
        }
        if (lane == 0) {
            el[n * 4 + h] = sl;
            er[n * 4 + h] = sr;
        }
    }
}

// generic (used for D=40 output layer): one thread per (n,h)
__global__ void elr_gen(const float* __restrict__ feat, const float* __restrict__ al,
                        const float* __restrict__ ar, float* __restrict__ el,
                        float* __restrict__ er, int Nn, int D) {
    int i = blockIdx.x * blockDim.x + threadIdx.x;
    if (i >= Nn * NH) return;
    int n = i / NH, h = i % NH;
    const float* f = feat + (size_t)n * NH * D + h * D;
    const float* a = al + h * D;
    const float* r = ar + h * D;
    float sl = 0.f, sr = 0.f;
    for (int d = 0; d < D; ++d) {
        float v = f[d];
        sl += v * a[d];
        sr += v * r[d];
    }
    el[i] = sl;
    er[i] = sr;
}

// ---------------- GAT aggregation, D=64 (layers 0,1), online softmax, elu -------
// Wave per node: lane owns features [4*lane, 4*lane+3]; head = lane>>4.
__global__ __launch_bounds__(256) void gat_agg64(const float* __restrict__ feat,
                                                 const float* __restrict__ el,
                                                 const float* __restrict__ er,
                                                 const int* __restrict__ rowptr,
                                                 const int* __restrict__ col,
                                                 const float* __restrict__ bias,
                                                 const float* __restrict__ res,
                                                 float* __restrict__ out) {
    int wave = threadIdx.x >> 6, lane = threadIdx.x & 63;
    int n = blockIdx.x * 4 + wave;
    if (n >= N_NODES) return;
    int h = lane >> 4;
    int f0 = lane * 4;
    int r0 = rowptr[n], r1 = rowptr[n + 1];
    float ern = er[n * 4 + h];

    float m = -1e30f, denom = 0.f;
    float4 acc = make_float4(0.f, 0.f, 0.f, 0.f);
    for (int k = r0; k < r1; ++k) {
        int s = col[k];
        float e = el[s * 4 + h] + ern;
        e = e > 0.f ? e : 0.2f * e;
        float4 f = *(const float4*)(feat + (size_t)s * 256 + f0);
        float mn = fmaxf(m, e);
        float scale = __expf(m - mn);   // first iter: expf(-huge) = 0
        float p = __expf(e - mn);
        m = mn;
        denom = denom * scale + p;
        acc.x = acc.x * scale + p * f.x;
        acc.y = acc.y * scale + p * f.y;
        acc.z = acc.z * scale + p * f.z;
        acc.w = acc.w * scale + p * f.w;
    }
    float inv = 1.f / denom;
    float4 b4 = *(const float4*)(bias + f0);
    float4 o = make_float4(acc.x * inv + b4.x, acc.y * inv + b4.y,
                           acc.z * inv + b4.z, acc.w * inv + b4.w);
    if (res) {
        float4 rv = *(const float4*)(res + (size_t)n * 256 + f0);
        o.x += rv.x; o.y += rv.y; o.z += rv.z; o.w += rv.w;
    }
    o.x = o.x > 0.f ? o.x : __expf(o.x) - 1.f;
    o.y = o.y > 0.f ? o.y : __expf(o.y) - 1.f;
    o.z = o.z > 0.f ? o.z : __expf(o.z) - 1.f;
    o.w = o.w > 0.f ? o.w : __expf(o.w) - 1.f;
    *(float4*)(out + (size_t)n * 256 + f0) = o;
}

// ---------------- GAT aggregation, D=40 output layer, online softmax + head-mean
// Wave per node: lanes 0..39 own float4 segments of the 160-wide row
// (head = lane/10; 4-elem segments never cross head boundary since 4 | 40).
__global__ __launch_bounds__(256) void gat_agg40(const float* __restrict__ feat,
                                                 const float* __restrict__ el,
                                                 const float* __restrict__ er,
                                                 const int* __restrict__ rowptr,
                                                 const int* __restrict__ col,
                                                 const float* __restrict__ bias,
                                                 const float* __restrict__ res,
                                                 float* __restrict__ out) {
    int wave = threadIdx.x >> 6, lane = threadIdx.x & 63;
    int n = blockIdx.x * 4 + wave;
    if (n >= N_NODES) return;
    float4 o = make_float4(0.f, 0.f, 0.f, 0.f);
    if (lane < 40) {
        int h = lane / 10;
        int f0 = lane * 4;
        int r0 = rowptr[n], r1 = rowptr[n + 1];
        float ern = er[n * 4 + h];
        float m = -1e30f, denom = 0.f;
        float4 acc = make_float4(0.f, 0.f, 0.f, 0.f);
        for (int k = r0; k < r1; ++k) {
            int s = col[k];
            float e = el[s * 4 + h] + ern;
            e = e > 0.f ? e : 0.2f * e;
            float4 f = *(const float4*)(feat + (size_t)s * 160 + f0);
            float mn = fmaxf(m, e);
            float scale = __expf(m - mn);
            float p = __expf(e - mn);
            m = mn;
            denom = denom * scale + p;
            acc.x = acc.x * scale + p * f.x;
            acc.y = acc.y * scale + p * f.y;
            acc.z = acc.z * scale + p * f.z;
            acc.w = acc.w * scale + p * f.w;
        }
        float inv = 1.f / denom;
        float4 b4 = *(const float4*)(bias + f0);
        float4 rv = *(const float4*)(res + (size_t)n * 160 + f0);
        o = make_float4(acc.x * inv + b4.x + rv.x, acc.y * inv + b4.y + rv.y,
                        acc.z * inv + b4.z + rv.z, acc.w * inv + b4.w + rv.w);
    }
    // head-mean: lanes l, l+10, l+20, l+30 hold the same class-quad across heads
    float4 t;
    t.x = o.x + __shfl_down(o.x, 10) + __shfl_down(o.x, 20) + __shfl_down(o.x, 30);
    t.y = o.y + __shfl_down(o.y, 10) + __shfl_down(o.y, 20) + __shfl_down(o.y, 30);
    t.z = o.z + __shfl_down(o.z, 10) + __shfl_down(o.z, 20) + __shfl_down(o.z, 30);
    t.w = o.w + __shfl_down(o.w, 10) + __shfl_down(o.w, 20) + __shfl_down(o.w, 30);
    if (lane < 10) {
        float4 r4 = make_float4(0.25f * t.x, 0.25f * t.y, 0.25f * t.z, 0.25f * t.w);
        *(float4*)(out + (size_t)n * 40 + lane * 4) = r4;
    }
}

// ---------------- launch ----------------

extern "C" void kernel_launch(void* const* d_in, const int* in_sizes, int n_in,
                              void* d_out, int out_size, void* d_ws, size_t ws_size,
                              hipStream_t stream) {
    const float* x    = (const float*)d_in[0];
    const int* src    = (const int*)d_in[1];
    const int* dst    = (const int*)d_in[2];
    const float* W0   = (const float*)d_in[3];
    const float* al0  = (const float*)d_in[4];
    const float* ar0  = (const float*)d_in[5];
    const float* b0   = (const float*)d_in[6];
    const float* W1   = (const float*)d_in[7];
    const float* al1  = (const float*)d_in[8];
    const float* ar1  = (const float*)d_in[9];
    const float* b1   = (const float*)d_in[10];
    const float* W2   = (const float*)d_in[11];
    const float* al2  = (const float*)d_in[12];
    const float* ar2  = (const float*)d_in[13];
    const float* b2   = (const float*)d_in[14];
    const float* Wres2 = (const float*)d_in[15];
    float* out = (float*)d_out;

    char* ws = (char*)d_ws;
    auto alloc = [&](size_t bytes) {
        char* p = ws;
        ws += (bytes + 255) & ~(size_t)255;
        return p;
    };
    int* rowptr   = (int*)alloc((N_NODES + 1) * sizeof(int));
    int* cursor   = (int*)alloc(N_NODES * sizeof(int));
    int* cnt      = (int*)alloc(N_NODES * sizeof(int));
    int* colA     = (int*)alloc(N_EDGES * sizeof(int));
    float* bufA   = (float*)alloc((size_t)N_NODES * 256 * sizeof(float));
    float* bufB   = (float*)alloc((size_t)N_NODES * 256 * sizeof(float));
    float* bufC   = (float*)alloc((size_t)N_NODES * 256 * sizeof(float));
    float* el     = (float*)alloc((size_t)N_NODES * NH * sizeof(float));
    float* er     = (float*)alloc((size_t)N_NODES * NH * sizeof(float));

    // CSR by dst (shared across all 3 layers)
    hipMemsetAsync(cnt, 0, N_NODES * sizeof(int), stream);
    k_hist<<<(N_EDGES + 255) / 256, 256, 0, stream>>>(dst, cnt, N_EDGES);
    k_scan<<<1, 1024, 0, stream>>>(cnt, rowptr, cursor, N_NODES);
    k_fill<<<(N_EDGES + 255) / 256, 256, 0, stream>>>(src, dst, cursor, colA, N_EDGES);

    dim3 gemm_grid0((256 + 127) / 128, (N_NODES + 127) / 128);
    dim3 gemm_grid2((160 + 63) / 64, (N_NODES + 127) / 128);
    int agg_grid = (N_NODES + 3) / 4;

    // layer 0: feat0 = x@W0 -> bufA ; h1 -> bufB
    gemm_f32<<<gemm_grid0, 256, 0, stream>>>(x, W0, bufA, N_NODES, 256, 256);
    elr64<<<(N_NODES + 3) / 4, 256, 0, stream>>>(bufA, al0, ar0, el, er, N_NODES);
    gat_agg64<<<agg_grid, 256, 0, stream>>>(bufA, el, er, rowptr, colA, b0, nullptr, bufB);

    // layer 1: feat1 = h1@W1 -> bufA ; h2 -> bufC (identity residual = bufB)
    gemm_f32<<<gemm_grid0, 256, 0, stream>>>(bufB, W1, bufA, N_NODES, 256, 256);
    elr64<<<(N_NODES + 3) / 4, 256, 0, stream>>>(bufA, al1, ar1, el, er, N_NODES);
    gat_agg64<<<agg_grid, 256, 0, stream>>>(bufA, el, er, rowptr, colA, b1, bufB, bufC);

    // layer 2: feat2 = h2@W2 -> bufA ; res2 = h2@Wres2 -> bufB (single dual pass)
    gemm_f32_dual<<<gemm_grid2, 256, 0, stream>>>(bufC, W2, Wres2, bufA, bufB,
                                                  N_NODES, 160, 256);
    elr_gen<<<(N_NODES * NH + 255) / 256, 256, 0, stream>>>(bufA, al2, ar2, el, er, N_NODES, NC);
    gat_agg40<<<agg_grid, 256, 0, stream>>>(bufA, el, er, rowptr, colA, b2, bufB, out);
}

// Round 6
// 978.264 us; speedup vs baseline: 1.1134x; 1.1134x over previous
//
#include <hip/hip_runtime.h>
#include <hip/hip_bf16.h>

#define N_NODES 50000
#define N_EDGES 800000
#define DIN 256
#define HID 64
#define NH 4
#define NC 40

typedef __attribute__((ext_vector_type(4))) short short4v;   // 8 B
typedef __attribute__((ext_vector_type(8))) short bf16x8;    // 16 B, MFMA A/B frag
typedef __attribute__((ext_vector_type(4))) float f32x4;     // 16 B, MFMA C/D frag

__device__ __forceinline__ unsigned short f2bf(float f) {
    unsigned u = __float_as_uint(f);
    unsigned r = (u + 0x7fffu + ((u >> 16) & 1u)) >> 16;  // RNE
    return (unsigned short)r;
}
__device__ __forceinline__ float bf2f(unsigned short b) {
    return __uint_as_float(((unsigned)b) << 16);
}

// ---------------- CSR build ----------------

__global__ void k_hist(const int* __restrict__ dst, int* __restrict__ cnt, int E) {
    int i = blockIdx.x * blockDim.x + threadIdx.x;
    if (i < E) atomicAdd(&cnt[dst[i]], 1);
}

__global__ __launch_bounds__(1024) void k_scan(const int* __restrict__ cnt,
                                               int* __restrict__ rowptr,
                                               int* __restrict__ cursor, int Nn) {
    __shared__ int lds[1024];
    int tid = threadIdx.x;
    const int CH = (Nn + 1023) / 1024;
    int base = tid * CH;
    int s = 0;
    for (int j = 0; j < CH; ++j) {
        int idx = base + j;
        if (idx < Nn) s += cnt[idx];
    }
    lds[tid] = s;
    __syncthreads();
    for (int off = 1; off < 1024; off <<= 1) {
        int v = (tid >= off) ? lds[tid - off] : 0;
        __syncthreads();
        lds[tid] += v;
        __syncthreads();
    }
    int run = (tid == 0) ? 0 : lds[tid - 1];
    for (int j = 0; j < CH; ++j) {
        int idx = base + j;
        if (idx < Nn) {
            rowptr[idx] = run;
            cursor[idx] = run;
            run += cnt[idx];
        }
    }
    if (tid == 1023) rowptr[Nn] = lds[1023];
}

__global__ void k_fill(const int* __restrict__ src, const int* __restrict__ dst,
                       int* __restrict__ cursor, int* __restrict__ col, int E) {
    int i = blockIdx.x * blockDim.x + threadIdx.x;
    if (i < E) {
        int p = atomicAdd(&cursor[dst[i]], 1);
        col[p] = src[i];
    }
}

// ---------------- weight convert: fp32 [K][NN] -> bf16 hi/lo transposed [NN][K] ----

__global__ void cvt_wT(const float* __restrict__ W, short* __restrict__ hT,
                       short* __restrict__ lT, int K, int NN) {
    int t = blockIdx.x * blockDim.x + threadIdx.x;
    if (t >= K * NN) return;
    int n = t / K, k = t - n * K;          // t = n*K + k -> coalesced writes
    float v = W[(size_t)k * NN + n];
    unsigned short h = f2bf(v);
    hT[t] = (short)h;
    lT[t] = (short)f2bf(v - bf2f(h));
}

// cat [W2 | Wres2] along N: NN=320, K=256
__global__ void cvt_wT_cat(const float* __restrict__ W2, const float* __restrict__ Wr,
                           short* __restrict__ hT, short* __restrict__ lT) {
    int t = blockIdx.x * blockDim.x + threadIdx.x;
    if (t >= 320 * 256) return;
    int n = t >> 8, k = t & 255;
    float v = (n < 160) ? W2[(size_t)k * 160 + n] : Wr[(size_t)k * 160 + (n - 160)];
    unsigned short h = f2bf(v);
    hT[t] = (short)h;
    lT[t] = (short)f2bf(v - bf2f(h));
}

// ---------------- bf16x3-split MFMA GEMM ----------------
// C[M][NN] = A[M][K] @ B[K][NN], A fp32 row-major (split in staging),
// B pre-split+transposed bf16 [NN][K]. BM=BN=128, BK=32, 256 threads (4 waves),
// each wave computes 64x64 via 4x4 fragments of 16x16x32.
// A ~ Ah+Al, B ~ Bh+Bl; acc += AhBh + AhBl + AlBh (fp32 accum).

#define SK 40  // LDS k-stride in shorts (32 + 8 pad; 80B row stride = 16B-aligned, 2-way banks)

__global__ __launch_bounds__(256) void gemm_mfma(const float* __restrict__ A,
                                                 const short* __restrict__ BhT,
                                                 const short* __restrict__ BlT,
                                                 float* __restrict__ C,
                                                 int M, int NN, int K) {
    __shared__ short Ah[128 * SK], Al[128 * SK], Bh[128 * SK], Bl[128 * SK];
    const int tid = threadIdx.x;
    const int bm = blockIdx.y * 128;
    const int bn = blockIdx.x * 128;
    const int w = tid >> 6, l = tid & 63;
    const int wr = w >> 1, wc = w & 1;      // wave tile (row, col) in 2x2
    const int rowf = l & 15, kg = l >> 4;   // fragment row, k-group

    f32x4 acc[4][4] = {};

    for (int k0 = 0; k0 < K; k0 += 32) {
        __syncthreads();  // previous iter's frag reads done before overwrite
        // ---- stage A (fp32 -> hi/lo bf16): 128 rows x 8 float4-chunks
#pragma unroll
        for (int it = 0; it < 4; ++it) {
            int chunk = tid + it * 256;
            int row = chunk >> 3, kc = chunk & 7;
            f32x4 v = {};
            int ar = bm + row;
            if (ar < M) v = *(const f32x4*)(A + (size_t)ar * K + k0 + kc * 4);
            short4v hi, lo;
#pragma unroll
            for (int j = 0; j < 4; ++j) {
                unsigned short h_ = f2bf(v[j]);
                hi[j] = (short)h_;
                lo[j] = (short)f2bf(v[j] - bf2f(h_));
            }
            *(short4v*)&Ah[row * SK + kc * 4] = hi;
            *(short4v*)&Al[row * SK + kc * 4] = lo;
        }
        // ---- stage B (pre-split bf16, transposed): 2 tiles x 128 rows x 4 chunks
#pragma unroll
        for (int it = 0; it < 4; ++it) {
            int chunk = tid + it * 256;
            int tile = chunk >> 9, c2 = chunk & 511;
            int nrow = c2 >> 2, kc = c2 & 3;
            bf16x8 v = {};
            int gn = bn + nrow;
            const short* srcT = tile ? BlT : BhT;
            if (gn < NN) v = *(const bf16x8*)(srcT + (size_t)gn * K + k0 + kc * 8);
            short* dstT = tile ? Bl : Bh;
            *(bf16x8*)&dstT[nrow * SK + kc * 8] = v;
        }
        __syncthreads();

        // ---- fragments + MFMA
        bf16x8 afh[4], afl[4], bfh[4], bfl[4];
#pragma unroll
        for (int m = 0; m < 4; ++m) {
            int off = (wr * 64 + m * 16 + rowf) * SK + kg * 8;
            afh[m] = *(const bf16x8*)&Ah[off];
            afl[m] = *(const bf16x8*)&Al[off];
        }
#pragma unroll
        for (int n = 0; n < 4; ++n) {
            int off = (wc * 64 + n * 16 + rowf) * SK + kg * 8;
            bfh[n] = *(const bf16x8*)&Bh[off];
            bfl[n] = *(const bf16x8*)&Bl[off];
        }
#pragma unroll
        for (int m = 0; m < 4; ++m)
#pragma unroll
            for (int n = 0; n < 4; ++n) {
                acc[m][n] = __builtin_amdgcn_mfma_f32_16x16x32_bf16(afh[m], bfh[n], acc[m][n], 0, 0, 0);
                acc[m][n] = __builtin_amdgcn_mfma_f32_16x16x32_bf16(afh[m], bfl[n], acc[m][n], 0, 0, 0);
                acc[m][n] = __builtin_amdgcn_mfma_f32_16x16x32_bf16(afl[m], bfh[n], acc[m][n], 0, 0, 0);
            }
    }

    // ---- epilogue: D[row=(l>>4)*4+r][col=l&15] (guide-verified layout)
#pragma unroll
    for (int m = 0; m < 4; ++m)
#pragma unroll
        for (int r = 0; r < 4; ++r) {
            int grow = bm + wr * 64 + m * 16 + kg * 4 + r;
            if (grow >= M) continue;
#pragma unroll
            for (int n = 0; n < 4; ++n) {
                int gcol = bn + wc * 64 + n * 16 + rowf;
                if (gcol < NN) C[(size_t)grow * NN + gcol] = acc[m][n][r];
            }
        }
}

// ---------------- el/er projections ----------------
__global__ __launch_bounds__(256) void elr64(const float* __restrict__ feat,
                                             const float* __restrict__ al,
                                             const float* __restrict__ ar,
                                             float* __restrict__ el,
                                             float* __restrict__ er, int Nn) {
    int wave = threadIdx.x >> 6, lane = threadIdx.x & 63;
    int n = blockIdx.x * 4 + wave;
    if (n >= Nn) return;
    const float* f = feat + (size_t)n * 256;
#pragma unroll
    for (int h = 0; h < 4; ++h) {
        float v = f[h * 64 + lane];
        float sl = v * al[h * 64 + lane];
        float sr = v * ar[h * 64 + lane];
#pragma unroll
        for (int off = 32; off; off >>= 1) {
            sl += __shfl_down(sl, off);
            sr += __shfl_down(sr, off);
        }
        if (lane == 0) {
            el[n * 4 + h] = sl;
            er[n * 4 + h] = sr;
        }
    }
}

// D=40 output layer: one thread per (n,h); feat has row stride ld
__global__ void elr_gen(const float* __restrict__ feat, int ld,
                        const float* __restrict__ al, const float* __restrict__ ar,
                        float* __restrict__ el, float* __restrict__ er, int Nn, int D) {
    int i = blockIdx.x * blockDim.x + threadIdx.x;
    if (i >= Nn * NH) return;
    int n = i / NH, h = i % NH;
    const float* f = feat + (size_t)n * ld + h * D;
    const float* a = al + h * D;
    const float* r = ar + h * D;
    float sl = 0.f, sr = 0.f;
    for (int d = 0; d < D; ++d) {
        float v = f[d];
        sl += v * a[d];
        sr += v * r[d];
    }
    el[i] = sl;
    er[i] = sr;
}

// ---------------- GAT aggregation, D=64 (layers 0,1), online softmax, elu -------
// Wave per node; explicit load-ahead pipeline (edge k+1's gathers issue before
// edge k's arithmetic). Branch conditions wave-uniform. Same op order as before.
__global__ __launch_bounds__(256) void gat_agg64(const float* __restrict__ feat,
                                                 const float* __restrict__ el,
                                                 const float* __restrict__ er,
                                                 const int* __restrict__ rowptr,
                                                 const int* __restrict__ col,
                                                 const float* __restrict__ bias,
                                                 const float* __restrict__ res,
                                                 float* __restrict__ out) {
    int wave = threadIdx.x >> 6, lane = threadIdx.x & 63;
    int n = blockIdx.x * 4 + wave;
    if (n >= N_NODES) return;
    int h = lane >> 4;
    int f0 = lane * 4;
    int r0 = rowptr[n], r1 = rowptr[n + 1];
    float ern = er[n * 4 + h];

    float m = -1e30f, denom = 0.f;
    float4 acc = make_float4(0.f, 0.f, 0.f, 0.f);

    // prologue: load edge r0 (self-loop guarantees r1 > r0)
    int s = col[r0];
    float elv = el[s * 4 + h];
    float4 f = *(const float4*)(feat + (size_t)s * 256 + f0);

    for (int k = r0; k < r1; ++k) {
        // issue next edge's loads before current arithmetic
        int s2;
        float elv2;
        float4 f2;
        bool more = (k + 1 < r1);
        if (more) {
            s2 = col[k + 1];
            elv2 = el[s2 * 4 + h];
            f2 = *(const float4*)(feat + (size_t)s2 * 256 + f0);
        }
        float e = elv + ern;
        e = e > 0.f ? e : 0.2f * e;
        float mn = fmaxf(m, e);
        float scale = __expf(m - mn);  // first iter: expf(-huge) = 0
        float p = __expf(e - mn);
        m = mn;
        denom = denom * scale + p;
        acc.x = acc.x * scale + p * f.x;
        acc.y = acc.y * scale + p * f.y;
        acc.z = acc.z * scale + p * f.z;
        acc.w = acc.w * scale + p * f.w;
        if (more) {
            elv = elv2;
            f = f2;
        }
    }
    float inv = 1.f / denom;
    float4 b4 = *(const float4*)(bias + f0);
    float4 o = make_float4(acc.x * inv + b4.x, acc.y * inv + b4.y,
                           acc.z * inv + b4.z, acc.w * inv + b4.w);
    if (res) {
        float4 rv = *(const float4*)(res + (size_t)n * 256 + f0);
        o.x += rv.x; o.y += rv.y; o.z += rv.z; o.w += rv.w;
    }
    o.x = o.x > 0.f ? o.x : __expf(o.x) - 1.f;
    o.y = o.y > 0.f ? o.y : __expf(o.y) - 1.f;
    o.z = o.z > 0.f ? o.z : __expf(o.z) - 1.f;
    o.w = o.w > 0.f ? o.w : __expf(o.w) - 1.f;
    *(float4*)(out + (size_t)n * 256 + f0) = o;
}

// ---------------- GAT aggregation, D=40 output layer, online softmax + head-mean
// feat/res have row stride ld (layer-2 outputs live in one [N][320] buffer).
__global__ __launch_bounds__(256) void gat_agg40(const float* __restrict__ feat, int ld,
                                                 const float* __restrict__ el,
                                                 const float* __restrict__ er,
                                                 const int* __restrict__ rowptr,
                                                 const int* __restrict__ col,
                                                 const float* __restrict__ bias,
                                                 const float* __restrict__ res,
                                                 float* __restrict__ out) {
    int wave = threadIdx.x >> 6, lane = threadIdx.x & 63;
    int n = blockIdx.x * 4 + wave;
    if (n >= N_NODES) return;
    float4 o = make_float4(0.f, 0.f, 0.f, 0.f);
    if (lane < 40) {
        int h = lane / 10;
        int f0 = lane * 4;
        int r0 = rowptr[n], r1 = rowptr[n + 1];
        float ern = er[n * 4 + h];
        float m = -1e30f, denom = 0.f;
        float4 acc = make_float4(0.f, 0.f, 0.f, 0.f);

        int s = col[r0];
        float elv = el[s * 4 + h];
        float4 f = *(const float4*)(feat + (size_t)s * ld + f0);

        for (int k = r0; k < r1; ++k) {
            int s2;
            float elv2;
            float4 f2;
            bool more = (k + 1 < r1);
            if (more) {
                s2 = col[k + 1];
                elv2 = el[s2 * 4 + h];
                f2 = *(const float4*)(feat + (size_t)s2 * ld + f0);
            }
            float e = elv + ern;
            e = e > 0.f ? e : 0.2f * e;
            float mn = fmaxf(m, e);
            float scale = __expf(m - mn);
            float p = __expf(e - mn);
            m = mn;
            denom = denom * scale + p;
            acc.x = acc.x * scale + p * f.x;
            acc.y = acc.y * scale + p * f.y;
            acc.z = acc.z * scale + p * f.z;
            acc.w = acc.w * scale + p * f.w;
            if (more) {
                elv = elv2;
                f = f2;
            }
        }
        float inv = 1.f / denom;
        float4 b4 = *(const float4*)(bias + f0);
        float4 rv = *(const float4*)(res + (size_t)n * ld + f0);
        o = make_float4(acc.x * inv + b4.x + rv.x, acc.y * inv + b4.y + rv.y,
                        acc.z * inv + b4.z + rv.z, acc.w * inv + b4.w + rv.w);
    }
    float4 t;
    t.x = o.x + __shfl_down(o.x, 10) + __shfl_down(o.x, 20) + __shfl_down(o.x, 30);
    t.y = o.y + __shfl_down(o.y, 10) + __shfl_down(o.y, 20) + __shfl_down(o.y, 30);
    t.z = o.z + __shfl_down(o.z, 10) + __shfl_down(o.z, 20) + __shfl_down(o.z, 30);
    t.w = o.w + __shfl_down(o.w, 10) + __shfl_down(o.w, 20) + __shfl_down(o.w, 30);
    if (lane < 10) {
        float4 r4 = make_float4(0.25f * t.x, 0.25f * t.y, 0.25f * t.z, 0.25f * t.w);
        *(float4*)(out + (size_t)n * 40 + lane * 4) = r4;
    }
}

// ---------------- launch ----------------

extern "C" void kernel_launch(void* const* d_in, const int* in_sizes, int n_in,
                              void* d_out, int out_size, void* d_ws, size_t ws_size,
                              hipStream_t stream) {
    const float* x    = (const float*)d_in[0];
    const int* src    = (const int*)d_in[1];
    const int* dst    = (const int*)d_in[2];
    const float* W0   = (const float*)d_in[3];
    const float* al0  = (const float*)d_in[4];
    const float* ar0  = (const float*)d_in[5];
    const float* b0   = (const float*)d_in[6];
    const float* W1   = (const float*)d_in[7];
    const float* al1  = (const float*)d_in[8];
    const float* ar1  = (const float*)d_in[9];
    const float* b1   = (const float*)d_in[10];
    const float* W2   = (const float*)d_in[11];
    const float* al2  = (const float*)d_in[12];
    const float* ar2  = (const float*)d_in[13];
    const float* b2   = (const float*)d_in[14];
    const float* Wres2 = (const float*)d_in[15];
    float* out = (float*)d_out;

    char* ws = (char*)d_ws;
    auto alloc = [&](size_t bytes) {
        char* p = ws;
        ws += (bytes + 255) & ~(size_t)255;
        return p;
    };
    int* rowptr   = (int*)alloc((N_NODES + 1) * sizeof(int));
    int* cursor   = (int*)alloc(N_NODES * sizeof(int));
    int* cnt      = (int*)alloc(N_NODES * sizeof(int));
    int* colA     = (int*)alloc(N_EDGES * sizeof(int));
    float* el     = (float*)alloc((size_t)N_NODES * NH * sizeof(float));
    float* er     = (float*)alloc((size_t)N_NODES * NH * sizeof(float));
    float* bufA   = (float*)alloc((size_t)N_NODES * 256 * sizeof(float));
    float* bufB   = (float*)alloc((size_t)N_NODES * 256 * sizeof(float));
    float* bufC   = (float*)alloc((size_t)N_NODES * 256 * sizeof(float));
    short* W0hT   = (short*)alloc(256 * 256 * sizeof(short));
    short* W0lT   = (short*)alloc(256 * 256 * sizeof(short));
    short* W1hT   = (short*)alloc(256 * 256 * sizeof(short));
    short* W1lT   = (short*)alloc(256 * 256 * sizeof(short));
    short* WchT   = (short*)alloc(320 * 256 * sizeof(short));
    short* WclT   = (short*)alloc(320 * 256 * sizeof(short));
    // layer-2 output [N][320]: overlays bufA+bufB (both dead by then; 64 MB <= 102.4 MB)
    float* bufD   = bufA;

    // CSR by dst (shared across all 3 layers)
    hipMemsetAsync(cnt, 0, N_NODES * sizeof(int), stream);
    k_hist<<<(N_EDGES + 255) / 256, 256, 0, stream>>>(dst, cnt, N_EDGES);
    k_scan<<<1, 1024, 0, stream>>>(cnt, rowptr, cursor, N_NODES);
    k_fill<<<(N_EDGES + 255) / 256, 256, 0, stream>>>(src, dst, cursor, colA, N_EDGES);

    // weight split+transpose (tiny)
    cvt_wT<<<(256 * 256 + 255) / 256, 256, 0, stream>>>(W0, W0hT, W0lT, 256, 256);
    cvt_wT<<<(256 * 256 + 255) / 256, 256, 0, stream>>>(W1, W1hT, W1lT, 256, 256);
    cvt_wT_cat<<<(320 * 256 + 255) / 256, 256, 0, stream>>>(W2, Wres2, WchT, WclT);

    dim3 g256(2, (N_NODES + 127) / 128);
    dim3 g320(3, (N_NODES + 127) / 128);
    int agg_grid = (N_NODES + 3) / 4;

    // layer 0: feat0 = x@W0 -> bufA ; h1 -> bufB
    gemm_mfma<<<g256, 256, 0, stream>>>(x, W0hT, W0lT, bufA, N_NODES, 256, 256);
    elr64<<<(N_NODES + 3) / 4, 256, 0, stream>>>(bufA, al0, ar0, el, er, N_NODES);
    gat_agg64<<<agg_grid, 256, 0, stream>>>(bufA, el, er, rowptr, colA, b0, nullptr, bufB);

    // layer 1: feat1 = h1@W1 -> bufA (feat0 dead) ; h2 -> bufC (res = bufB)
    gemm_mfma<<<g256, 256, 0, stream>>>(bufB, W1hT, W1lT, bufA, N_NODES, 256, 256);
    elr64<<<(N_NODES + 3) / 4, 256, 0, stream>>>(bufA, al1, ar1, el, er, N_NODES);
    gat_agg64<<<agg_grid, 256, 0, stream>>>(bufA, el, er, rowptr, colA, b1, bufB, bufC);

    // layer 2: [feat2 | res2] = h2 @ [W2 | Wres2] -> bufD [N][320]
    gemm_mfma<<<g320, 256, 0, stream>>>(bufC, WchT, WclT, bufD, N_NODES, 320, 256);
    elr_gen<<<(N_NODES * NH + 255) / 256, 256, 0, stream>>>(bufD, 320, al2, ar2, el, er, N_NODES, NC);
    gat_agg40<<<agg_grid, 256, 0, stream>>>(bufD, 320, el, er, rowptr, colA, b2, bufD + 160, out);
}

// Round 7
// 902.926 us; speedup vs baseline: 1.2063x; 1.0834x over previous
//
#include <hip/hip_runtime.h>
#include <hip/hip_bf16.h>
#include <hip/hip_fp16.h>

#define N_NODES 50000
#define N_EDGES 800000
#define DIN 256
#define HID 64
#define NH 4
#define NC 40

typedef __attribute__((ext_vector_type(4))) short short4v;   // 8 B
typedef __attribute__((ext_vector_type(8))) short bf16x8;    // 16 B, MFMA A/B frag
typedef __attribute__((ext_vector_type(4))) float f32x4;     // 16 B, MFMA C/D frag

__device__ __forceinline__ unsigned short f2bf(float f) {
    unsigned u = __float_as_uint(f);
    unsigned r = (u + 0x7fffu + ((u >> 16) & 1u)) >> 16;  // RNE
    return (unsigned short)r;
}
__device__ __forceinline__ float bf2f(unsigned short b) {
    return __uint_as_float(((unsigned)b) << 16);
}

// ---------------- CSR build ----------------

__global__ void k_hist(const int* __restrict__ dst, int* __restrict__ cnt, int E) {
    int i = blockIdx.x * blockDim.x + threadIdx.x;
    if (i < E) atomicAdd(&cnt[dst[i]], 1);
}

__global__ __launch_bounds__(1024) void k_scan(const int* __restrict__ cnt,
                                               int* __restrict__ rowptr,
                                               int* __restrict__ cursor, int Nn) {
    __shared__ int lds[1024];
    int tid = threadIdx.x;
    const int CH = (Nn + 1023) / 1024;
    int base = tid * CH;
    int s = 0;
    for (int j = 0; j < CH; ++j) {
        int idx = base + j;
        if (idx < Nn) s += cnt[idx];
    }
    lds[tid] = s;
    __syncthreads();
    for (int off = 1; off < 1024; off <<= 1) {
        int v = (tid >= off) ? lds[tid - off] : 0;
        __syncthreads();
        lds[tid] += v;
        __syncthreads();
    }
    int run = (tid == 0) ? 0 : lds[tid - 1];
    for (int j = 0; j < CH; ++j) {
        int idx = base + j;
        if (idx < Nn) {
            rowptr[idx] = run;
            cursor[idx] = run;
            run += cnt[idx];
        }
    }
    if (tid == 1023) rowptr[Nn] = lds[1023];
}

__global__ void k_fill(const int* __restrict__ src, const int* __restrict__ dst,
                       int* __restrict__ cursor, int* __restrict__ col, int E) {
    int i = blockIdx.x * blockDim.x + threadIdx.x;
    if (i < E) {
        int p = atomicAdd(&cursor[dst[i]], 1);
        col[p] = src[i];
    }
}

// ---------------- weight convert: fp32 [K][NN] -> bf16 hi/lo transposed [NN][K] ----

__global__ void cvt_wT(const float* __restrict__ W, short* __restrict__ hT,
                       short* __restrict__ lT, int K, int NN) {
    int t = blockIdx.x * blockDim.x + threadIdx.x;
    if (t >= K * NN) return;
    int n = t / K, k = t - n * K;          // t = n*K + k -> coalesced writes
    float v = W[(size_t)k * NN + n];
    unsigned short h = f2bf(v);
    hT[t] = (short)h;
    lT[t] = (short)f2bf(v - bf2f(h));
}

// cat [W2 | Wres2] along N: NN=320, K=256
__global__ void cvt_wT_cat(const float* __restrict__ W2, const float* __restrict__ Wr,
                           short* __restrict__ hT, short* __restrict__ lT) {
    int t = blockIdx.x * blockDim.x + threadIdx.x;
    if (t >= 320 * 256) return;
    int n = t >> 8, k = t & 255;
    float v = (n < 160) ? W2[(size_t)k * 160 + n] : Wr[(size_t)k * 160 + (n - 160)];
    unsigned short h = f2bf(v);
    hT[t] = (short)h;
    lT[t] = (short)f2bf(v - bf2f(h));
}

// ---------------- bf16x3-split MFMA GEMM, fp16 output ----------------
// C[M][NN] (fp16) = A[M][K] (fp32) @ B[K][NN], B pre-split+transposed bf16 [NN][K].
// BM=BN=128, BK=32, 256 threads (4 waves), wave = 64x64 via 4x4 frags of 16x16x32.
// A ~ Ah+Al, B ~ Bh+Bl; acc += AhBh + AhBl + AlBh (fp32 accum).

#define SK 40  // LDS k-stride in shorts (32 + 8 pad; 80B row stride = 16B-aligned, 2-way banks)

__global__ __launch_bounds__(256) void gemm_mfma(const float* __restrict__ A,
                                                 const short* __restrict__ BhT,
                                                 const short* __restrict__ BlT,
                                                 __half* __restrict__ C,
                                                 int M, int NN, int K) {
    __shared__ short Ah[128 * SK], Al[128 * SK], Bh[128 * SK], Bl[128 * SK];
    const int tid = threadIdx.x;
    const int bm = blockIdx.y * 128;
    const int bn = blockIdx.x * 128;
    const int w = tid >> 6, l = tid & 63;
    const int wr = w >> 1, wc = w & 1;      // wave tile (row, col) in 2x2
    const int rowf = l & 15, kg = l >> 4;   // fragment row, k-group

    f32x4 acc[4][4] = {};

    for (int k0 = 0; k0 < K; k0 += 32) {
        __syncthreads();  // previous iter's frag reads done before overwrite
        // ---- stage A (fp32 -> hi/lo bf16): 128 rows x 8 float4-chunks
#pragma unroll
        for (int it = 0; it < 4; ++it) {
            int chunk = tid + it * 256;
            int row = chunk >> 3, kc = chunk & 7;
            f32x4 v = {};
            int ar = bm + row;
            if (ar < M) v = *(const f32x4*)(A + (size_t)ar * K + k0 + kc * 4);
            short4v hi, lo;
#pragma unroll
            for (int j = 0; j < 4; ++j) {
                unsigned short h_ = f2bf(v[j]);
                hi[j] = (short)h_;
                lo[j] = (short)f2bf(v[j] - bf2f(h_));
            }
            *(short4v*)&Ah[row * SK + kc * 4] = hi;
            *(short4v*)&Al[row * SK + kc * 4] = lo;
        }
        // ---- stage B (pre-split bf16, transposed): 2 tiles x 128 rows x 4 chunks
#pragma unroll
        for (int it = 0; it < 4; ++it) {
            int chunk = tid + it * 256;
            int tile = chunk >> 9, c2 = chunk & 511;
            int nrow = c2 >> 2, kc = c2 & 3;
            bf16x8 v = {};
            int gn = bn + nrow;
            const short* srcT = tile ? BlT : BhT;
            if (gn < NN) v = *(const bf16x8*)(srcT + (size_t)gn * K + k0 + kc * 8);
            short* dstT = tile ? Bl : Bh;
            *(bf16x8*)&dstT[nrow * SK + kc * 8] = v;
        }
        __syncthreads();

        // ---- fragments + MFMA
        bf16x8 afh[4], afl[4], bfh[4], bfl[4];
#pragma unroll
        for (int m = 0; m < 4; ++m) {
            int off = (wr * 64 + m * 16 + rowf) * SK + kg * 8;
            afh[m] = *(const bf16x8*)&Ah[off];
            afl[m] = *(const bf16x8*)&Al[off];
        }
#pragma unroll
        for (int n = 0; n < 4; ++n) {
            int off = (wc * 64 + n * 16 + rowf) * SK + kg * 8;
            bfh[n] = *(const bf16x8*)&Bh[off];
            bfl[n] = *(const bf16x8*)&Bl[off];
        }
#pragma unroll
        for (int m = 0; m < 4; ++m)
#pragma unroll
            for (int n = 0; n < 4; ++n) {
                acc[m][n] = __builtin_amdgcn_mfma_f32_16x16x32_bf16(afh[m], bfh[n], acc[m][n], 0, 0, 0);
                acc[m][n] = __builtin_amdgcn_mfma_f32_16x16x32_bf16(afh[m], bfl[n], acc[m][n], 0, 0, 0);
                acc[m][n] = __builtin_amdgcn_mfma_f32_16x16x32_bf16(afl[m], bfh[n], acc[m][n], 0, 0, 0);
            }
    }

    // ---- epilogue: D[row=(l>>4)*4+r][col=l&15] (guide-verified layout), fp16 store
#pragma unroll
    for (int m = 0; m < 4; ++m)
#pragma unroll
        for (int r = 0; r < 4; ++r) {
            int grow = bm + wr * 64 + m * 16 + kg * 4 + r;
            if (grow >= M) continue;
#pragma unroll
            for (int n = 0; n < 4; ++n) {
                int gcol = bn + wc * 64 + n * 16 + rowf;
                if (gcol < NN) C[(size_t)grow * NN + gcol] = __float2half(acc[m][n][r]);
            }
        }
}

// ---------------- el/er projections (fp16 feat) ----------------
__global__ __launch_bounds__(256) void elr64(const __half* __restrict__ feat,
                                             const float* __restrict__ al,
                                             const float* __restrict__ ar,
                                             float* __restrict__ el,
                                             float* __restrict__ er, int Nn) {
    int wave = threadIdx.x >> 6, lane = threadIdx.x & 63;
    int n = blockIdx.x * 4 + wave;
    if (n >= Nn) return;
    const __half* f = feat + (size_t)n * 256;
#pragma unroll
    for (int h = 0; h < 4; ++h) {
        float v = __half2float(f[h * 64 + lane]);
        float sl = v * al[h * 64 + lane];
        float sr = v * ar[h * 64 + lane];
#pragma unroll
        for (int off = 32; off; off >>= 1) {
            sl += __shfl_down(sl, off);
            sr += __shfl_down(sr, off);
        }
        if (lane == 0) {
            el[n * 4 + h] = sl;
            er[n * 4 + h] = sr;
        }
    }
}

// D=40 output layer: one thread per (n,h); fp16 feat with row stride ld
__global__ void elr_gen(const __half* __restrict__ feat, int ld,
                        const float* __restrict__ al, const float* __restrict__ ar,
                        float* __restrict__ el, float* __restrict__ er, int Nn, int D) {
    int i = blockIdx.x * blockDim.x + threadIdx.x;
    if (i >= Nn * NH) return;
    int n = i / NH, h = i % NH;
    const __half* f = feat + (size_t)n * ld + h * D;
    const float* a = al + h * D;
    const float* r = ar + h * D;
    float sl = 0.f, sr = 0.f;
    for (int d = 0; d < D; ++d) {
        float v = __half2float(f[d]);
        sl += v * a[d];
        sr += v * r[d];
    }
    el[i] = sl;
    er[i] = sr;
}

// ---------------- GAT aggregation, D=64 (layers 0,1), online softmax, elu -------
// Wave per node: lane owns features [4*lane..4*lane+3] (8B fp16); head = lane>>4.
// 1-deep load-ahead pipeline; fp32 accumulation; fp32 res/out.
__global__ __launch_bounds__(256) void gat_agg64(const __half* __restrict__ feat,
                                                 const float* __restrict__ el,
                                                 const float* __restrict__ er,
                                                 const int* __restrict__ rowptr,
                                                 const int* __restrict__ col,
                                                 const float* __restrict__ bias,
                                                 const float* __restrict__ res,
                                                 float* __restrict__ out) {
    int wave = threadIdx.x >> 6, lane = threadIdx.x & 63;
    int n = blockIdx.x * 4 + wave;
    if (n >= N_NODES) return;
    int h = lane >> 4;
    int f0 = lane * 4;
    int r0 = rowptr[n], r1 = rowptr[n + 1];
    float ern = er[n * 4 + h];

    float m = -1e30f, denom = 0.f;
    float4 acc = make_float4(0.f, 0.f, 0.f, 0.f);

    // prologue: load edge r0 (self-loop guarantees r1 > r0)
    int s = col[r0];
    float elv = el[s * 4 + h];
    uint2 u = *(const uint2*)(feat + (size_t)s * 256 + f0);

    for (int k = r0; k < r1; ++k) {
        int s2;
        float elv2;
        uint2 u2;
        bool more = (k + 1 < r1);
        if (more) {
            s2 = col[k + 1];
            elv2 = el[s2 * 4 + h];
            u2 = *(const uint2*)(feat + (size_t)s2 * 256 + f0);
        }
        float e = elv + ern;
        e = e > 0.f ? e : 0.2f * e;
        float mn = fmaxf(m, e);
        float scale = __expf(m - mn);  // first iter: expf(-huge) = 0
        float p = __expf(e - mn);
        m = mn;
        float2 flo = __half22float2(*(const __half2*)&u.x);
        float2 fhi = __half22float2(*(const __half2*)&u.y);
        denom = denom * scale + p;
        acc.x = acc.x * scale + p * flo.x;
        acc.y = acc.y * scale + p * flo.y;
        acc.z = acc.z * scale + p * fhi.x;
        acc.w = acc.w * scale + p * fhi.y;
        if (more) {
            elv = elv2;
            u = u2;
        }
    }
    float inv = 1.f / denom;
    float4 b4 = *(const float4*)(bias + f0);
    float4 o = make_float4(acc.x * inv + b4.x, acc.y * inv + b4.y,
                           acc.z * inv + b4.z, acc.w * inv + b4.w);
    if (res) {
        float4 rv = *(const float4*)(res + (size_t)n * 256 + f0);
        o.x += rv.x; o.y += rv.y; o.z += rv.z; o.w += rv.w;
    }
    o.x = o.x > 0.f ? o.x : __expf(o.x) - 1.f;
    o.y = o.y > 0.f ? o.y : __expf(o.y) - 1.f;
    o.z = o.z > 0.f ? o.z : __expf(o.z) - 1.f;
    o.w = o.w > 0.f ? o.w : __expf(o.w) - 1.f;
    *(float4*)(out + (size_t)n * 256 + f0) = o;
}

// ---------------- GAT aggregation, D=40 output layer, online softmax + head-mean
// fp16 feat/res with row stride ld (layer-2 outputs in one fp16 [N][320] buffer).
__global__ __launch_bounds__(256) void gat_agg40(const __half* __restrict__ feat, int ld,
                                                 const float* __restrict__ el,
                                                 const float* __restrict__ er,
                                                 const int* __restrict__ rowptr,
                                                 const int* __restrict__ col,
                                                 const float* __restrict__ bias,
                                                 const __half* __restrict__ res,
                                                 float* __restrict__ out) {
    int wave = threadIdx.x >> 6, lane = threadIdx.x & 63;
    int n = blockIdx.x * 4 + wave;
    if (n >= N_NODES) return;
    float4 o = make_float4(0.f, 0.f, 0.f, 0.f);
    if (lane < 40) {
        int h = lane / 10;
        int f0 = lane * 4;
        int r0 = rowptr[n], r1 = rowptr[n + 1];
        float ern = er[n * 4 + h];
        float m = -1e30f, denom = 0.f;
        float4 acc = make_float4(0.f, 0.f, 0.f, 0.f);

        int s = col[r0];
        float elv = el[s * 4 + h];
        uint2 u = *(const uint2*)(feat + (size_t)s * ld + f0);

        for (int k = r0; k < r1; ++k) {
            int s2;
            float elv2;
            uint2 u2;
            bool more = (k + 1 < r1);
            if (more) {
                s2 = col[k + 1];
                elv2 = el[s2 * 4 + h];
                u2 = *(const uint2*)(feat + (size_t)s2 * ld + f0);
            }
            float e = elv + ern;
            e = e > 0.f ? e : 0.2f * e;
            float mn = fmaxf(m, e);
            float scale = __expf(m - mn);
            float p = __expf(e - mn);
            m = mn;
            float2 flo = __half22float2(*(const __half2*)&u.x);
            float2 fhi = __half22float2(*(const __half2*)&u.y);
            denom = denom * scale + p;
            acc.x = acc.x * scale + p * flo.x;
            acc.y = acc.y * scale + p * flo.y;
            acc.z = acc.z * scale + p * fhi.x;
            acc.w = acc.w * scale + p * fhi.y;
            if (more) {
                elv = elv2;
                u = u2;
            }
        }
        float inv = 1.f / denom;
        float4 b4 = *(const float4*)(bias + f0);
        uint2 ur = *(const uint2*)(res + (size_t)n * ld + f0);
        float2 rlo = __half22float2(*(const __half2*)&ur.x);
        float2 rhi = __half22float2(*(const __half2*)&ur.y);
        o = make_float4(acc.x * inv + b4.x + rlo.x, acc.y * inv + b4.y + rlo.y,
                        acc.z * inv + b4.z + rhi.x, acc.w * inv + b4.w + rhi.y);
    }
    float4 t;
    t.x = o.x + __shfl_down(o.x, 10) + __shfl_down(o.x, 20) + __shfl_down(o.x, 30);
    t.y = o.y + __shfl_down(o.y, 10) + __shfl_down(o.y, 20) + __shfl_down(o.y, 30);
    t.z = o.z + __shfl_down(o.z, 10) + __shfl_down(o.z, 20) + __shfl_down(o.z, 30);
    t.w = o.w + __shfl_down(o.w, 10) + __shfl_down(o.w, 20) + __shfl_down(o.w, 30);
    if (lane < 10) {
        float4 r4 = make_float4(0.25f * t.x, 0.25f * t.y, 0.25f * t.z, 0.25f * t.w);
        *(float4*)(out + (size_t)n * 40 + lane * 4) = r4;
    }
}

// ---------------- launch ----------------

extern "C" void kernel_launch(void* const* d_in, const int* in_sizes, int n_in,
                              void* d_out, int out_size, void* d_ws, size_t ws_size,
                              hipStream_t stream) {
    const float* x    = (const float*)d_in[0];
    const int* src    = (const int*)d_in[1];
    const int* dst    = (const int*)d_in[2];
    const float* W0   = (const float*)d_in[3];
    const float* al0  = (const float*)d_in[4];
    const float* ar0  = (const float*)d_in[5];
    const float* b0   = (const float*)d_in[6];
    const float* W1   = (const float*)d_in[7];
    const float* al1  = (const float*)d_in[8];
    const float* ar1  = (const float*)d_in[9];
    const float* b1   = (const float*)d_in[10];
    const float* W2   = (const float*)d_in[11];
    const float* al2  = (const float*)d_in[12];
    const float* ar2  = (const float*)d_in[13];
    const float* b2   = (const float*)d_in[14];
    const float* Wres2 = (const float*)d_in[15];
    float* out = (float*)d_out;

    char* ws = (char*)d_ws;
    auto alloc = [&](size_t bytes) {
        char* p = ws;
        ws += (bytes + 255) & ~(size_t)255;
        return p;
    };
    int* rowptr   = (int*)alloc((N_NODES + 1) * sizeof(int));
    int* cursor   = (int*)alloc(N_NODES * sizeof(int));
    int* cnt      = (int*)alloc(N_NODES * sizeof(int));
    int* colA     = (int*)alloc(N_EDGES * sizeof(int));
    float* el     = (float*)alloc((size_t)N_NODES * NH * sizeof(float));
    float* er     = (float*)alloc((size_t)N_NODES * NH * sizeof(float));
    float* bufB   = (float*)alloc((size_t)N_NODES * 256 * sizeof(float));   // h1
    float* bufC   = (float*)alloc((size_t)N_NODES * 256 * sizeof(float));   // h2
    __half* featH = (__half*)alloc((size_t)N_NODES * 256 * sizeof(__half)); // feat0/feat1
    __half* featH2= (__half*)alloc((size_t)N_NODES * 320 * sizeof(__half)); // [feat2|res2]
    short* W0hT   = (short*)alloc(256 * 256 * sizeof(short));
    short* W0lT   = (short*)alloc(256 * 256 * sizeof(short));
    short* W1hT   = (short*)alloc(256 * 256 * sizeof(short));
    short* W1lT   = (short*)alloc(256 * 256 * sizeof(short));
    short* WchT   = (short*)alloc(320 * 256 * sizeof(short));
    short* WclT   = (short*)alloc(320 * 256 * sizeof(short));

    // CSR by dst (shared across all 3 layers)
    hipMemsetAsync(cnt, 0, N_NODES * sizeof(int), stream);
    k_hist<<<(N_EDGES + 255) / 256, 256, 0, stream>>>(dst, cnt, N_EDGES);
    k_scan<<<1, 1024, 0, stream>>>(cnt, rowptr, cursor, N_NODES);
    k_fill<<<(N_EDGES + 255) / 256, 256, 0, stream>>>(src, dst, cursor, colA, N_EDGES);

    // weight split+transpose (tiny)
    cvt_wT<<<(256 * 256 + 255) / 256, 256, 0, stream>>>(W0, W0hT, W0lT, 256, 256);
    cvt_wT<<<(256 * 256 + 255) / 256, 256, 0, stream>>>(W1, W1hT, W1lT, 256, 256);
    cvt_wT_cat<<<(320 * 256 + 255) / 256, 256, 0, stream>>>(W2, Wres2, WchT, WclT);

    dim3 g256(2, (N_NODES + 127) / 128);
    dim3 g320(3, (N_NODES + 127) / 128);
    int agg_grid = (N_NODES + 3) / 4;

    // layer 0: feat0 = x@W0 -> featH (fp16) ; h1 -> bufB (fp32)
    gemm_mfma<<<g256, 256, 0, stream>>>(x, W0hT, W0lT, featH, N_NODES, 256, 256);
    elr64<<<(N_NODES + 3) / 4, 256, 0, stream>>>(featH, al0, ar0, el, er, N_NODES);
    gat_agg64<<<agg_grid, 256, 0, stream>>>(featH, el, er, rowptr, colA, b0, nullptr, bufB);

    // layer 1: feat1 = h1@W1 -> featH (feat0 dead) ; h2 -> bufC (res = bufB)
    gemm_mfma<<<g256, 256, 0, stream>>>(bufB, W1hT, W1lT, featH, N_NODES, 256, 256);
    elr64<<<(N_NODES + 3) / 4, 256, 0, stream>>>(featH, al1, ar1, el, er, N_NODES);
    gat_agg64<<<agg_grid, 256, 0, stream>>>(featH, el, er, rowptr, colA, b1, bufB, bufC);

    // layer 2: [feat2 | res2] = h2 @ [W2 | Wres2] -> featH2 fp16 [N][320]
    gemm_mfma<<<g320, 256, 0, stream>>>(bufC, WchT, WclT, featH2, N_NODES, 320, 256);
    elr_gen<<<(N_NODES * NH + 255) / 256, 256, 0, stream>>>(featH2, 320, al2, ar2, el, er, N_NODES, NC);
    gat_agg40<<<agg_grid, 256, 0, stream>>>(featH2, 320, el, er, rowptr, colA, b2, featH2 + 160, out);
}

// Round 9
// 692.489 us; speedup vs baseline: 1.5728x; 1.3039x over previous
//
#include <hip/hip_runtime.h>
#include <hip/hip_bf16.h>
#include <hip/hip_fp16.h>

#define N_NODES 50000
#define N_EDGES 800000
#define DIN 256
#define HID 64
#define NH 4
#define NC 40

typedef __attribute__((ext_vector_type(4))) short short4v;   // 8 B
typedef __attribute__((ext_vector_type(8))) short bf16x8;    // 16 B, MFMA A/B frag
typedef __attribute__((ext_vector_type(4))) float f32x4;     // 16 B, MFMA C/D frag

__device__ __forceinline__ unsigned short f2bf(float f) {
    unsigned u = __float_as_uint(f);
    unsigned r = (u + 0x7fffu + ((u >> 16) & 1u)) >> 16;  // RNE
    return (unsigned short)r;
}
__device__ __forceinline__ float bf2f(unsigned short b) {
    return __uint_as_float(((unsigned)b) << 16);
}

// ---------------- CSR build ----------------

__global__ void k_hist(const int* __restrict__ dst, int* __restrict__ cnt, int E) {
    int i = blockIdx.x * blockDim.x + threadIdx.x;
    if (i < E) atomicAdd(&cnt[dst[i]], 1);
}

// two-level parallel scan: 49 blocks x 1024 counts
#define SCAN_BLOCKS 49

__global__ __launch_bounds__(256) void k_bsum(const int* __restrict__ cnt,
                                              int* __restrict__ bsum, int Nn) {
    __shared__ int red[256];
    int b = blockIdx.x, t = threadIdx.x;
    int base = b * 1024 + t * 4;
    int s = 0;
    if (base + 3 < Nn) {
        int4 v = *(const int4*)(cnt + base);
        s = v.x + v.y + v.z + v.w;
    } else {
        for (int j = 0; j < 4; ++j)
            if (base + j < Nn) s += cnt[base + j];
    }
    red[t] = s;
    __syncthreads();
    for (int off = 128; off; off >>= 1) {
        if (t < off) red[t] += red[t + off];
        __syncthreads();
    }
    if (t == 0) bsum[b] = red[0];
}

__global__ void k_bscan(const int* __restrict__ bsum, int* __restrict__ bpre, int nb) {
    int l = threadIdx.x;  // single wave of 64
    int x = (l < nb) ? bsum[l] : 0;
    int v = x;
    for (int off = 1; off < 64; off <<= 1) {
        int u = __shfl_up(v, off);
        if (l >= off) v += u;
    }
    if (l < nb) bpre[l] = v - x;  // exclusive
}

__global__ __launch_bounds__(256) void k_scatter(const int* __restrict__ cnt,
                                                 const int* __restrict__ bpre,
                                                 int* __restrict__ rowptr,
                                                 int* __restrict__ cursor, int Nn) {
    __shared__ int red[256];
    int b = blockIdx.x, t = threadIdx.x;
    int base = b * 1024 + t * 4;
    int c[4];
    int s = 0;
    for (int j = 0; j < 4; ++j) {
        int idx = base + j;
        c[j] = (idx < Nn) ? cnt[idx] : 0;
        s += c[j];
    }
    red[t] = s;
    __syncthreads();
    for (int off = 1; off < 256; off <<= 1) {
        int v = (t >= off) ? red[t - off] : 0;
        __syncthreads();
        red[t] += v;
        __syncthreads();
    }
    int run = red[t] - s + bpre[b];  // exclusive prefix for this thread's 4 counts
    for (int j = 0; j < 4; ++j) {
        int idx = base + j;
        if (idx < Nn) {
            rowptr[idx] = run;
            cursor[idx] = run;
            run += c[j];
        }
    }
    if (b == 0 && t == 0) rowptr[Nn] = N_EDGES;  // every edge is histogrammed
}

__global__ void k_fill(const int* __restrict__ src, const int* __restrict__ dst,
                       int* __restrict__ cursor, int* __restrict__ col, int E) {
    int i = blockIdx.x * blockDim.x + threadIdx.x;
    if (i < E) {
        int p = atomicAdd(&cursor[dst[i]], 1);
        col[p] = src[i];
    }
}

// ---------------- weight convert: fp32 [K][NN] -> bf16 hi/lo transposed [NN][K] ----

__global__ void cvt_wT(const float* __restrict__ W, short* __restrict__ hT,
                       short* __restrict__ lT, int K, int NN) {
    int t = blockIdx.x * blockDim.x + threadIdx.x;
    if (t >= K * NN) return;
    int n = t / K, k = t - n * K;          // t = n*K + k -> coalesced writes
    float v = W[(size_t)k * NN + n];
    unsigned short h = f2bf(v);
    hT[t] = (short)h;
    lT[t] = (short)f2bf(v - bf2f(h));
}

// cat [W2 | Wres2] along N: NN=320, K=256
__global__ void cvt_wT_cat(const float* __restrict__ W2, const float* __restrict__ Wr,
                           short* __restrict__ hT, short* __restrict__ lT) {
    int t = blockIdx.x * blockDim.x + threadIdx.x;
    if (t >= 320 * 256) return;
    int n = t >> 8, k = t & 255;
    float v = (n < 160) ? W2[(size_t)k * 160 + n] : Wr[(size_t)k * 160 + (n - 160)];
    unsigned short h = f2bf(v);
    hT[t] = (short)h;
    lT[t] = (short)f2bf(v - bf2f(h));
}

// ---------------- bf16x3-split MFMA GEMM, fp16 output ----------------
// C[M][NN] (fp16) = A[M][K] (fp32) @ B[K][NN], B pre-split+transposed bf16 [NN][K].
// BM=BN=128, BK=32, 256 threads (4 waves), wave = 64x64 via 4x4 frags of 16x16x32.
// A ~ Ah+Al, B ~ Bh+Bl; acc += AhBh + AhBl + AlBh (fp32 accum).

#define SK 40  // LDS k-stride in shorts (32 + 8 pad; 80B row stride = 16B-aligned, 2-way banks)

__global__ __launch_bounds__(256) void gemm_mfma(const float* __restrict__ A,
                                                 const short* __restrict__ BhT,
                                                 const short* __restrict__ BlT,
                                                 __half* __restrict__ C,
                                                 int M, int NN, int K) {
    __shared__ short Ah[128 * SK], Al[128 * SK], Bh[128 * SK], Bl[128 * SK];
    const int tid = threadIdx.x;
    const int bm = blockIdx.y * 128;
    const int bn = blockIdx.x * 128;
    const int w = tid >> 6, l = tid & 63;
    const int wr = w >> 1, wc = w & 1;      // wave tile (row, col) in 2x2
    const int rowf = l & 15, kg = l >> 4;   // fragment row, k-group

    f32x4 acc[4][4] = {};

    for (int k0 = 0; k0 < K; k0 += 32) {
        __syncthreads();  // previous iter's frag reads done before overwrite
        // ---- stage A (fp32 -> hi/lo bf16): 128 rows x 8 float4-chunks
#pragma unroll
        for (int it = 0; it < 4; ++it) {
            int chunk = tid + it * 256;
            int row = chunk >> 3, kc = chunk & 7;
            f32x4 v = {};
            int ar = bm + row;
            if (ar < M) v = *(const f32x4*)(A + (size_t)ar * K + k0 + kc * 4);
            short4v hi, lo;
#pragma unroll
            for (int j = 0; j < 4; ++j) {
                unsigned short h_ = f2bf(v[j]);
                hi[j] = (short)h_;
                lo[j] = (short)f2bf(v[j] - bf2f(h_));
            }
            *(short4v*)&Ah[row * SK + kc * 4] = hi;
            *(short4v*)&Al[row * SK + kc * 4] = lo;
        }
        // ---- stage B (pre-split bf16, transposed): 2 tiles x 128 rows x 4 chunks
#pragma unroll
        for (int it = 0; it < 4; ++it) {
            int chunk = tid + it * 256;
            int tile = chunk >> 9, c2 = chunk & 511;
            int nrow = c2 >> 2, kc = c2 & 3;
            bf16x8 v = {};
            int gn = bn + nrow;
            const short* srcT = tile ? BlT : BhT;
            if (gn < NN) v = *(const bf16x8*)(srcT + (size_t)gn * K + k0 + kc * 8);
            short* dstT = tile ? Bl : Bh;
            *(bf16x8*)&dstT[nrow * SK + kc * 8] = v;
        }
        __syncthreads();

        // ---- fragments + MFMA
        bf16x8 afh[4], afl[4], bfh[4], bfl[4];
#pragma unroll
        for (int m = 0; m < 4; ++m) {
            int off = (wr * 64 + m * 16 + rowf) * SK + kg * 8;
            afh[m] = *(const bf16x8*)&Ah[off];
            afl[m] = *(const bf16x8*)&Al[off];
        }
#pragma unroll
        for (int n = 0; n < 4; ++n) {
            int off = (wc * 64 + n * 16 + rowf) * SK + kg * 8;
            bfh[n] = *(const bf16x8*)&Bh[off];
            bfl[n] = *(const bf16x8*)&Bl[off];
        }
#pragma unroll
        for (int m = 0; m < 4; ++m)
#pragma unroll
            for (int n = 0; n < 4; ++n) {
                acc[m][n] = __builtin_amdgcn_mfma_f32_16x16x32_bf16(afh[m], bfh[n], acc[m][n], 0, 0, 0);
                acc[m][n] = __builtin_amdgcn_mfma_f32_16x16x32_bf16(afh[m], bfl[n], acc[m][n], 0, 0, 0);
                acc[m][n] = __builtin_amdgcn_mfma_f32_16x16x32_bf16(afl[m], bfh[n], acc[m][n], 0, 0, 0);
            }
    }

    // ---- epilogue: D[row=(l>>4)*4+r][col=l&15] (guide-verified layout), fp16 store
#pragma unroll
    for (int m = 0; m < 4; ++m)
#pragma unroll
        for (int r = 0; r < 4; ++r) {
            int grow = bm + wr * 64 + m * 16 + kg * 4 + r;
            if (grow >= M) continue;
#pragma unroll
            for (int n = 0; n < 4; ++n) {
                int gcol = bn + wc * 64 + n * 16 + rowf;
                if (gcol < NN) C[(size_t)grow * NN + gcol] = __float2half(acc[m][n][r]);
            }
        }
}

// ---------------- el/er projections (fp16 feat, vectorized) ----------------
// Wave per node; 16 lanes per head; lane reads 4 contiguous halves (uint2).
__global__ __launch_bounds__(256) void elr64(const __half* __restrict__ feat,
                                             const float* __restrict__ al,
                                             const float* __restrict__ ar,
                                             float* __restrict__ el,
                                             float* __restrict__ er, int Nn) {
    int wave = threadIdx.x >> 6, lane = threadIdx.x & 63;
    int n = blockIdx.x * 4 + wave;
    if (n >= Nn) return;
    int g = lane >> 4;            // head
    int i4 = (lane & 15) * 4;     // element offset within head
    int off = g * 64 + i4;
    uint2 u = *(const uint2*)(feat + (size_t)n * 256 + off);
    float4 a4 = *(const float4*)(al + off);
    float4 r4 = *(const float4*)(ar + off);
    float2 lo = __half22float2(*(const __half2*)&u.x);
    float2 hi = __half22float2(*(const __half2*)&u.y);
    float sl = lo.x * a4.x + lo.y * a4.y + hi.x * a4.z + hi.y * a4.w;
    float sr = lo.x * r4.x + lo.y * r4.y + hi.x * r4.z + hi.y * r4.w;
#pragma unroll
    for (int o = 8; o; o >>= 1) {
        sl += __shfl_down(sl, o);
        sr += __shfl_down(sr, o);
    }
    if ((lane & 15) == 0) {
        el[n * 4 + g] = sl;
        er[n * 4 + g] = sr;
    }
}

// D=40 output layer: one thread per (n,h); fp16 feat with row stride ld
__global__ void elr_gen(const __half* __restrict__ feat, int ld,
                        const float* __restrict__ al, const float* __restrict__ ar,
                        float* __restrict__ el, float* __restrict__ er, int Nn, int D) {
    int i = blockIdx.x * blockDim.x + threadIdx.x;
    if (i >= Nn * NH) return;
    int n = i / NH, h = i % NH;
    const __half* f = feat + (size_t)n * ld + h * D;
    const float* a = al + h * D;
    const float* r = ar + h * D;
    float sl = 0.f, sr = 0.f;
#pragma unroll
    for (int q = 0; q < 10; ++q) {  // D=40 = 10 x uint2
        uint2 u = *(const uint2*)(f + q * 4);
        float2 lo = __half22float2(*(const __half2*)&u.x);
        float2 hi = __half22float2(*(const __half2*)&u.y);
        sl += lo.x * a[q * 4] + lo.y * a[q * 4 + 1] + hi.x * a[q * 4 + 2] + hi.y * a[q * 4 + 3];
        sr += lo.x * r[q * 4] + lo.y * r[q * 4 + 1] + hi.x * r[q * 4 + 2] + hi.y * r[q * 4 + 3];
    }
    el[i] = sl;
    er[i] = sr;
}

// ---------------- GAT aggregation, D=64 (layers 0,1), online softmax, elu -------
// Wave per node: lane owns features [4*lane..4*lane+3] (8B fp16); head = lane>>4.
// 4-deep load-ahead pipeline (shift registers, no dynamic indexing).
__global__ __launch_bounds__(256) void gat_agg64(const __half* __restrict__ feat,
                                                 const float* __restrict__ el,
                                                 const float* __restrict__ er,
                                                 const int* __restrict__ rowptr,
                                                 const int* __restrict__ col,
                                                 const float* __restrict__ bias,
                                                 const float* __restrict__ res,
                                                 float* __restrict__ out) {
    int wave = threadIdx.x >> 6, lane = threadIdx.x & 63;
    int n = blockIdx.x * 4 + wave;
    if (n >= N_NODES) return;
    int h = lane >> 4;
    int f0 = lane * 4;
    int r0 = rowptr[n], r1 = rowptr[n + 1];
    float ern = er[n * 4 + h];

    float m = -1e30f, denom = 0.f;
    float4 acc = make_float4(0.f, 0.f, 0.f, 0.f);

    // pipeline slots (edges consumed in order; slot j holds edge kl_j)
    float e0 = 0.f, e1 = 0.f, e2 = 0.f, e3 = 0.f;
    uint2 u0 = {0, 0}, u1 = {0, 0}, u2 = {0, 0}, u3 = {0, 0};
    int kl = r0;
    if (kl < r1) { int s = col[kl]; e0 = el[s * 4 + h]; u0 = *(const uint2*)(feat + (size_t)s * 256 + f0); ++kl; }
    if (kl < r1) { int s = col[kl]; e1 = el[s * 4 + h]; u1 = *(const uint2*)(feat + (size_t)s * 256 + f0); ++kl; }
    if (kl < r1) { int s = col[kl]; e2 = el[s * 4 + h]; u2 = *(const uint2*)(feat + (size_t)s * 256 + f0); ++kl; }
    if (kl < r1) { int s = col[kl]; e3 = el[s * 4 + h]; u3 = *(const uint2*)(feat + (size_t)s * 256 + f0); ++kl; }

    for (int k = r0; k < r1; ++k) {
        float e = e0 + ern;
        e = e > 0.f ? e : 0.2f * e;
        float mn = fmaxf(m, e);
        float scale = __expf(m - mn);  // first iter: expf(-huge) = 0
        float p = __expf(e - mn);
        m = mn;
        float2 flo = __half22float2(*(const __half2*)&u0.x);
        float2 fhi = __half22float2(*(const __half2*)&u0.y);
        denom = denom * scale + p;
        acc.x = acc.x * scale + p * flo.x;
        acc.y = acc.y * scale + p * flo.y;
        acc.z = acc.z * scale + p * fhi.x;
        acc.w = acc.w * scale + p * fhi.y;
        // shift pipeline
        e0 = e1; u0 = u1;
        e1 = e2; u1 = u2;
        e2 = e3; u2 = u3;
        if (kl < r1) { int s = col[kl]; e3 = el[s * 4 + h]; u3 = *(const uint2*)(feat + (size_t)s * 256 + f0); ++kl; }
    }
    float inv = 1.f / denom;
    float4 b4 = *(const float4*)(bias + f0);
    float4 o = make_float4(acc.x * inv + b4.x, acc.y * inv + b4.y,
                           acc.z * inv + b4.z, acc.w * inv + b4.w);
    if (res) {
        float4 rv = *(const float4*)(res + (size_t)n * 256 + f0);
        o.x += rv.x; o.y += rv.y; o.z += rv.z; o.w += rv.w;
    }
    o.x = o.x > 0.f ? o.x : __expf(o.x) - 1.f;
    o.y = o.y > 0.f ? o.y : __expf(o.y) - 1.f;
    o.z = o.z > 0.f ? o.z : __expf(o.z) - 1.f;
    o.w = o.w > 0.f ? o.w : __expf(o.w) - 1.f;
    *(float4*)(out + (size_t)n * 256 + f0) = o;
}

// ---------------- GAT aggregation, D=40 output layer, online softmax + head-mean
// fp16 feat/res with row stride ld; 4-deep load-ahead pipeline.
__global__ __launch_bounds__(256) void gat_agg40(const __half* __restrict__ feat, int ld,
                                                 const float* __restrict__ el,
                                                 const float* __restrict__ er,
                                                 const int* __restrict__ rowptr,
                                                 const int* __restrict__ col,
                                                 const float* __restrict__ bias,
                                                 const __half* __restrict__ res,
                                                 float* __restrict__ out) {
    int wave = threadIdx.x >> 6, lane = threadIdx.x & 63;
    int n = blockIdx.x * 4 + wave;
    if (n >= N_NODES) return;
    float4 o = make_float4(0.f, 0.f, 0.f, 0.f);
    if (lane < 40) {
        int h = lane / 10;
        int f0 = lane * 4;
        int r0 = rowptr[n], r1 = rowptr[n + 1];
        float ern = er[n * 4 + h];
        float m = -1e30f, denom = 0.f;
        float4 acc = make_float4(0.f, 0.f, 0.f, 0.f);

        float e0 = 0.f, e1 = 0.f, e2 = 0.f, e3 = 0.f;
        uint2 u0 = {0, 0}, u1 = {0, 0}, u2 = {0, 0}, u3 = {0, 0};
        int kl = r0;
        if (kl < r1) { int s = col[kl]; e0 = el[s * 4 + h]; u0 = *(const uint2*)(feat + (size_t)s * ld + f0); ++kl; }
        if (kl < r1) { int s = col[kl]; e1 = el[s * 4 + h]; u1 = *(const uint2*)(feat + (size_t)s * ld + f0); ++kl; }
        if (kl < r1) { int s = col[kl]; e2 = el[s * 4 + h]; u2 = *(const uint2*)(feat + (size_t)s * ld + f0); ++kl; }
        if (kl < r1) { int s = col[kl]; e3 = el[s * 4 + h]; u3 = *(const uint2*)(feat + (size_t)s * ld + f0); ++kl; }

        for (int k = r0; k < r1; ++k) {
            float e = e0 + ern;
            e = e > 0.f ? e : 0.2f * e;
            float mn = fmaxf(m, e);
            float scale = __expf(m - mn);
            float p = __expf(e - mn);
            m = mn;
            float2 flo = __half22float2(*(const __half2*)&u0.x);
            float2 fhi = __half22float2(*(const __half2*)&u0.y);
            denom = denom * scale + p;
            acc.x = acc.x * scale + p * flo.x;
            acc.y = acc.y * scale + p * flo.y;
            acc.z = acc.z * scale + p * fhi.x;
            acc.w = acc.w * scale + p * fhi.y;
            e0 = e1; u0 = u1;
            e1 = e2; u1 = u2;
            e2 = e3; u2 = u3;
            if (kl < r1) { int s = col[kl]; e3 = el[s * 4 + h]; u3 = *(const uint2*)(feat + (size_t)s * ld + f0); ++kl; }
        }
        float inv = 1.f / denom;
        float4 b4 = *(const float4*)(bias + f0);
        uint2 ur = *(const uint2*)(res + (size_t)n * ld + f0);
        float2 rlo = __half22float2(*(const __half2*)&ur.x);
        float2 rhi = __half22float2(*(const __half2*)&ur.y);
        o = make_float4(acc.x * inv + b4.x + rlo.x, acc.y * inv + b4.y + rlo.y,
                        acc.z * inv + b4.z + rhi.x, acc.w * inv + b4.w + rhi.y);
    }
    float4 t;
    t.x = o.x + __shfl_down(o.x, 10) + __shfl_down(o.x, 20) + __shfl_down(o.x, 30);
    t.y = o.y + __shfl_down(o.y, 10) + __shfl_down(o.y, 20) + __shfl_down(o.y, 30);
    t.z = o.z + __shfl_down(o.z, 10) + __shfl_down(o.z, 20) + __shfl_down(o.z, 30);
    t.w = o.w + __shfl_down(o.w, 10) + __shfl_down(o.w, 20) + __shfl_down(o.w, 30);
    if (lane < 10) {
        float4 r4 = make_float4(0.25f * t.x, 0.25f * t.y, 0.25f * t.z, 0.25f * t.w);
        *(float4*)(out + (size_t)n * 40 + lane * 4) = r4;
    }
}

// ---------------- launch ----------------

extern "C" void kernel_launch(void* const* d_in, const int* in_sizes, int n_in,
                              void* d_out, int out_size, void* d_ws, size_t ws_size,
                              hipStream_t stream) {
    const float* x    = (const float*)d_in[0];
    const int* src    = (const int*)d_in[1];
    const int* dst    = (const int*)d_in[2];
    const float* W0   = (const float*)d_in[3];
    const float* al0  = (const float*)d_in[4];
    const float* ar0  = (const float*)d_in[5];
    const float* b0   = (const float*)d_in[6];
    const float* W1   = (const float*)d_in[7];
    const float* al1  = (const float*)d_in[8];
    const float* ar1  = (const float*)d_in[9];
    const float* b1   = (const float*)d_in[10];
    const float* W2   = (const float*)d_in[11];
    const float* al2  = (const float*)d_in[12];
    const float* ar2  = (const float*)d_in[13];
    const float* b2   = (const float*)d_in[14];
    const float* Wres2 = (const float*)d_in[15];
    float* out = (float*)d_out;

    char* ws = (char*)d_ws;
    auto alloc = [&](size_t bytes) {
        char* p = ws;
        ws += (bytes + 255) & ~(size_t)255;
        return p;
    };
    int* rowptr   = (int*)alloc((N_NODES + 1) * sizeof(int));
    int* cursor   = (int*)alloc(N_NODES * sizeof(int));
    int* cnt      = (int*)alloc(N_NODES * sizeof(int));
    int* bsum     = (int*)alloc(SCAN_BLOCKS * sizeof(int));
    int* bpre     = (int*)alloc(SCAN_BLOCKS * sizeof(int));
    int* colA     = (int*)alloc(N_EDGES * sizeof(int));
    float* el     = (float*)alloc((size_t)N_NODES * NH * sizeof(float));
    float* er     = (float*)alloc((size_t)N_NODES * NH * sizeof(float));
    float* bufB   = (float*)alloc((size_t)N_NODES * 256 * sizeof(float));   // h1
    float* bufC   = (float*)alloc((size_t)N_NODES * 256 * sizeof(float));   // h2
    __half* featH = (__half*)alloc((size_t)N_NODES * 256 * sizeof(__half)); // feat0/feat1
    __half* featH2= (__half*)alloc((size_t)N_NODES * 320 * sizeof(__half)); // [feat2|res2]
    short* W0hT   = (short*)alloc(256 * 256 * sizeof(short));
    short* W0lT   = (short*)alloc(256 * 256 * sizeof(short));
    short* W1hT   = (short*)alloc(256 * 256 * sizeof(short));
    short* W1lT   = (short*)alloc(256 * 256 * sizeof(short));
    short* WchT   = (short*)alloc(320 * 256 * sizeof(short));
    short* WclT   = (short*)alloc(320 * 256 * sizeof(short));

    // CSR by dst (shared across all 3 layers) — two-level parallel scan
    hipMemsetAsync(cnt, 0, N_NODES * sizeof(int), stream);
    k_hist<<<(N_EDGES + 255) / 256, 256, 0, stream>>>(dst, cnt, N_EDGES);
    k_bsum<<<SCAN_BLOCKS, 256, 0, stream>>>(cnt, bsum, N_NODES);
    k_bscan<<<1, 64, 0, stream>>>(bsum, bpre, SCAN_BLOCKS);
    k_scatter<<<SCAN_BLOCKS, 256, 0, stream>>>(cnt, bpre, rowptr, cursor, N_NODES);
    k_fill<<<(N_EDGES + 255) / 256, 256, 0, stream>>>(src, dst, cursor, colA, N_EDGES);

    // weight split+transpose (tiny)
    cvt_wT<<<(256 * 256 + 255) / 256, 256, 0, stream>>>(W0, W0hT, W0lT, 256, 256);
    cvt_wT<<<(256 * 256 + 255) / 256, 256, 0, stream>>>(W1, W1hT, W1lT, 256, 256);
    cvt_wT_cat<<<(320 * 256 + 255) / 256, 256, 0, stream>>>(W2, Wres2, WchT, WclT);

    dim3 g256(2, (N_NODES + 127) / 128);
    dim3 g320(3, (N_NODES + 127) / 128);
    int agg_grid = (N_NODES + 3) / 4;

    // layer 0: feat0 = x@W0 -> featH (fp16) ; h1 -> bufB (fp32)
    gemm_mfma<<<g256, 256, 0, stream>>>(x, W0hT, W0lT, featH, N_NODES, 256, 256);
    elr64<<<(N_NODES + 3) / 4, 256, 0, stream>>>(featH, al0, ar0, el, er, N_NODES);
    gat_agg64<<<agg_grid, 256, 0, stream>>>(featH, el, er, rowptr, colA, b0, nullptr, bufB);

    // layer 1: feat1 = h1@W1 -> featH (feat0 dead) ; h2 -> bufC (res = bufB)
    gemm_mfma<<<g256, 256, 0, stream>>>(bufB, W1hT, W1lT, featH, N_NODES, 256, 256);
    elr64<<<(N_NODES + 3) / 4, 256, 0, stream>>>(featH, al1, ar1, el, er, N_NODES);
    gat_agg64<<<agg_grid, 256, 0, stream>>>(featH, el, er, rowptr, colA, b1, bufB, bufC);

    // layer 2: [feat2 | res2] = h2 @ [W2 | Wres2] -> featH2 fp16 [N][320]
    gemm_mfma<<<g320, 256, 0, stream>>>(bufC, WchT, WclT, featH2, N_NODES, 320, 256);
    elr_gen<<<(N_NODES * NH + 255) / 256, 256, 0, stream>>>(featH2, 320, al2, ar2, el, er, N_NODES, NC);
    gat_agg40<<<agg_grid, 256, 0, stream>>>(featH2, 320, el, er, rowptr, colA, b2, featH2 + 160, out);
}

// Round 12
// 648.181 us; speedup vs baseline: 1.6803x; 1.0684x over previous
//
#include <hip/hip_runtime.h>
#include <hip/hip_bf16.h>
#include <hip/hip_fp16.h>

#define N_NODES 50000
#define N_EDGES 800000
#define DIN 256
#define HID 64
#define NH 4
#define NC 40

typedef __attribute__((ext_vector_type(4))) short short4v;   // 8 B
typedef __attribute__((ext_vector_type(8))) short bf16x8;    // 16 B, MFMA A/B frag
typedef __attribute__((ext_vector_type(4))) float f32x4;     // 16 B, MFMA C/D frag

__device__ __forceinline__ unsigned short f2bf(float f) {
    unsigned u = __float_as_uint(f);
    unsigned r = (u + 0x7fffu + ((u >> 16) & 1u)) >> 16;  // RNE
    return (unsigned short)r;
}
__device__ __forceinline__ float bf2f(unsigned short b) {
    return __uint_as_float(((unsigned)b) << 16);
}

// ---------------- CSR build ----------------

__global__ void k_hist(const int* __restrict__ dst, int* __restrict__ cnt, int E) {
    int i = blockIdx.x * blockDim.x + threadIdx.x;
    if (i < E) atomicAdd(&cnt[dst[i]], 1);
}

// two-level parallel scan: 49 blocks x 1024 counts
#define SCAN_BLOCKS 49

__global__ __launch_bounds__(256) void k_bsum(const int* __restrict__ cnt,
                                              int* __restrict__ bsum, int Nn) {
    __shared__ int red[256];
    int b = blockIdx.x, t = threadIdx.x;
    int base = b * 1024 + t * 4;
    int s = 0;
    if (base + 3 < Nn) {
        int4 v = *(const int4*)(cnt + base);
        s = v.x + v.y + v.z + v.w;
    } else {
        for (int j = 0; j < 4; ++j)
            if (base + j < Nn) s += cnt[base + j];
    }
    red[t] = s;
    __syncthreads();
    for (int off = 128; off; off >>= 1) {
        if (t < off) red[t] += red[t + off];
        __syncthreads();
    }
    if (t == 0) bsum[b] = red[0];
}

__global__ void k_bscan(const int* __restrict__ bsum, int* __restrict__ bpre, int nb) {
    int l = threadIdx.x;  // single wave of 64
    int x = (l < nb) ? bsum[l] : 0;
    int v = x;
    for (int off = 1; off < 64; off <<= 1) {
        int u = __shfl_up(v, off);
        if (l >= off) v += u;
    }
    if (l < nb) bpre[l] = v - x;  // exclusive
}

__global__ __launch_bounds__(256) void k_scatter(const int* __restrict__ cnt,
                                                 const int* __restrict__ bpre,
                                                 int* __restrict__ rowptr,
                                                 int* __restrict__ cursor, int Nn) {
    __shared__ int red[256];
    int b = blockIdx.x, t = threadIdx.x;
    int base = b * 1024 + t * 4;
    int c[4];
    int s = 0;
    for (int j = 0; j < 4; ++j) {
        int idx = base + j;
        c[j] = (idx < Nn) ? cnt[idx] : 0;
        s += c[j];
    }
    red[t] = s;
    __syncthreads();
    for (int off = 1; off < 256; off <<= 1) {
        int v = (t >= off) ? red[t - off] : 0;
        __syncthreads();
        red[t] += v;
        __syncthreads();
    }
    int run = red[t] - s + bpre[b];  // exclusive prefix for this thread's 4 counts
    for (int j = 0; j < 4; ++j) {
        int idx = base + j;
        if (idx < Nn) {
            rowptr[idx] = run;
            cursor[idx] = run;
            run += c[j];
        }
    }
    if (b == 0 && t == 0) rowptr[Nn] = N_EDGES;  // every edge is histogrammed
}

__global__ void k_fill(const int* __restrict__ src, const int* __restrict__ dst,
                       int* __restrict__ cursor, int* __restrict__ col, int E) {
    int i = blockIdx.x * blockDim.x + threadIdx.x;
    if (i < E) {
        int p = atomicAdd(&cursor[dst[i]], 1);
        col[p] = src[i];
    }
}

// ---------------- weight convert: fp32 [K][NN] -> bf16 hi/lo transposed [NN][K] ----

__global__ void cvt_wT(const float* __restrict__ W, short* __restrict__ hT,
                       short* __restrict__ lT, int K, int NN) {
    int t = blockIdx.x * blockDim.x + threadIdx.x;
    if (t >= K * NN) return;
    int n = t / K, k = t - n * K;          // t = n*K + k -> coalesced writes
    float v = W[(size_t)k * NN + n];
    unsigned short h = f2bf(v);
    hT[t] = (short)h;
    lT[t] = (short)f2bf(v - bf2f(h));
}

// cat [W2 | Wres2] along N: NN=320, K=256
__global__ void cvt_wT_cat(const float* __restrict__ W2, const float* __restrict__ Wr,
                           short* __restrict__ hT, short* __restrict__ lT) {
    int t = blockIdx.x * blockDim.x + threadIdx.x;
    if (t >= 320 * 256) return;
    int n = t >> 8, k = t & 255;
    float v = (n < 160) ? W2[(size_t)k * 160 + n] : Wr[(size_t)k * 160 + (n - 160)];
    unsigned short h = f2bf(v);
    hT[t] = (short)h;
    lT[t] = (short)f2bf(v - bf2f(h));
}

// ---------------- bf16x3-split MFMA GEMM, fp16 output ----------------
// C[M][NN] (fp16) = A[M][K] (fp32) @ B[K][NN], B pre-split+transposed bf16 [NN][K].
// BM=BN=128, BK=32, 256 threads (4 waves), wave = 64x64 via 4x4 frags of 16x16x32.
// A ~ Ah+Al, B ~ Bh+Bl; acc += AhBh + AhBl + AlBh (fp32 accum).

#define SK 40  // LDS k-stride in shorts (32 + 8 pad; 80B row stride = 16B-aligned, 2-way banks)

__global__ __launch_bounds__(256) void gemm_mfma(const float* __restrict__ A,
                                                 const short* __restrict__ BhT,
                                                 const short* __restrict__ BlT,
                                                 __half* __restrict__ C,
                                                 int M, int NN, int K) {
    __shared__ short Ah[128 * SK], Al[128 * SK], Bh[128 * SK], Bl[128 * SK];
    const int tid = threadIdx.x;
    const int bm = blockIdx.y * 128;
    const int bn = blockIdx.x * 128;
    const int w = tid >> 6, l = tid & 63;
    const int wr = w >> 1, wc = w & 1;      // wave tile (row, col) in 2x2
    const int rowf = l & 15, kg = l >> 4;   // fragment row, k-group

    f32x4 acc[4][4] = {};

    for (int k0 = 0; k0 < K; k0 += 32) {
        __syncthreads();  // previous iter's frag reads done before overwrite
        // ---- stage A (fp32 -> hi/lo bf16): 128 rows x 8 float4-chunks
#pragma unroll
        for (int it = 0; it < 4; ++it) {
            int chunk = tid + it * 256;
            int row = chunk >> 3, kc = chunk & 7;
            f32x4 v = {};
            int ar = bm + row;
            if (ar < M) v = *(const f32x4*)(A + (size_t)ar * K + k0 + kc * 4);
            short4v hi, lo;
#pragma unroll
            for (int j = 0; j < 4; ++j) {
                unsigned short h_ = f2bf(v[j]);
                hi[j] = (short)h_;
                lo[j] = (short)f2bf(v[j] - bf2f(h_));
            }
            *(short4v*)&Ah[row * SK + kc * 4] = hi;
            *(short4v*)&Al[row * SK + kc * 4] = lo;
        }
        // ---- stage B (pre-split bf16, transposed): 2 tiles x 128 rows x 4 chunks
#pragma unroll
        for (int it = 0; it < 4; ++it) {
            int chunk = tid + it * 256;
            int tile = chunk >> 9, c2 = chunk & 511;
            int nrow = c2 >> 2, kc = c2 & 3;
            bf16x8 v = {};
            int gn = bn + nrow;
            const short* srcT = tile ? BlT : BhT;
            if (gn < NN) v = *(const bf16x8*)(srcT + (size_t)gn * K + k0 + kc * 8);
            short* dstT = tile ? Bl : Bh;
            *(bf16x8*)&dstT[nrow * SK + kc * 8] = v;
        }
        __syncthreads();

        // ---- fragments + MFMA
        bf16x8 afh[4], afl[4], bfh[4], bfl[4];
#pragma unroll
        for (int m = 0; m < 4; ++m) {
            int off = (wr * 64 + m * 16 + rowf) * SK + kg * 8;
            afh[m] = *(const bf16x8*)&Ah[off];
            afl[m] = *(const bf16x8*)&Al[off];
        }
#pragma unroll
        for (int n = 0; n < 4; ++n) {
            int off = (wc * 64 + n * 16 + rowf) * SK + kg * 8;
            bfh[n] = *(const bf16x8*)&Bh[off];
            bfl[n] = *(const bf16x8*)&Bl[off];
        }
#pragma unroll
        for (int m = 0; m < 4; ++m)
#pragma unroll
            for (int n = 0; n < 4; ++n) {
                acc[m][n] = __builtin_amdgcn_mfma_f32_16x16x32_bf16(afh[m], bfh[n], acc[m][n], 0, 0, 0);
                acc[m][n] = __builtin_amdgcn_mfma_f32_16x16x32_bf16(afh[m], bfl[n], acc[m][n], 0, 0, 0);
                acc[m][n] = __builtin_amdgcn_mfma_f32_16x16x32_bf16(afl[m], bfh[n], acc[m][n], 0, 0, 0);
            }
    }

    // ---- epilogue: D[row=(l>>4)*4+r][col=l&15] (guide-verified layout), fp16 store
#pragma unroll
    for (int m = 0; m < 4; ++m)
#pragma unroll
        for (int r = 0; r < 4; ++r) {
            int grow = bm + wr * 64 + m * 16 + kg * 4 + r;
            if (grow >= M) continue;
#pragma unroll
            for (int n = 0; n < 4; ++n) {
                int gcol = bn + wc * 64 + n * 16 + rowf;
                if (gcol < NN) C[(size_t)grow * NN + gcol] = __float2half(acc[m][n][r]);
            }
        }
}

// ---------------- el/er projections (fp16 feat, vectorized) ----------------
// Wave per node; 16 lanes per head; lane reads 4 contiguous halves (uint2).
__global__ __launch_bounds__(256) void elr64(const __half* __restrict__ feat,
                                             const float* __restrict__ al,
                                             const float* __restrict__ ar,
                                             float* __restrict__ el,
                                             float* __restrict__ er, int Nn) {
    int wave = threadIdx.x >> 6, lane = threadIdx.x & 63;
    int n = blockIdx.x * 4 + wave;
    if (n >= Nn) return;
    int g = lane >> 4;            // head
    int i4 = (lane & 15) * 4;     // element offset within head
    int off = g * 64 + i4;
    uint2 u = *(const uint2*)(feat + (size_t)n * 256 + off);
    float4 a4 = *(const float4*)(al + off);
    float4 r4 = *(const float4*)(ar + off);
    float2 lo = __half22float2(*(const __half2*)&u.x);
    float2 hi = __half22float2(*(const __half2*)&u.y);
    float sl = lo.x * a4.x + lo.y * a4.y + hi.x * a4.z + hi.y * a4.w;
    float sr = lo.x * r4.x + lo.y * r4.y + hi.x * r4.z + hi.y * r4.w;
#pragma unroll
    for (int o = 8; o; o >>= 1) {
        sl += __shfl_down(sl, o);
        sr += __shfl_down(sr, o);
    }
    if ((lane & 15) == 0) {
        el[n * 4 + g] = sl;
        er[n * 4 + g] = sr;
    }
}

// D=40 output layer: one thread per (n,h); fp16 feat with row stride ld
__global__ void elr_gen(const __half* __restrict__ feat, int ld,
                        const float* __restrict__ al, const float* __restrict__ ar,
                        float* __restrict__ el, float* __restrict__ er, int Nn, int D) {
    int i = blockIdx.x * blockDim.x + threadIdx.x;
    if (i >= Nn * NH) return;
    int n = i / NH, h = i % NH;
    const __half* f = feat + (size_t)n * ld + h * D;
    const float* a = al + h * D;
    const float* r = ar + h * D;
    float sl = 0.f, sr = 0.f;
#pragma unroll
    for (int q = 0; q < 10; ++q) {  // D=40 = 10 x uint2
        uint2 u = *(const uint2*)(f + q * 4);
        float2 lo = __half22float2(*(const __half2*)&u.x);
        float2 hi = __half22float2(*(const __half2*)&u.y);
        sl += lo.x * a[q * 4] + lo.y * a[q * 4 + 1] + hi.x * a[q * 4 + 2] + hi.y * a[q * 4 + 3];
        sr += lo.x * r[q * 4] + lo.y * r[q * 4 + 1] + hi.x * r[q * 4 + 2] + hi.y * r[q * 4 + 3];
    }
    el[i] = sl;
    er[i] = sr;
}

// ---------------- per-(node,head) max of el over in-neighbors ----------------
// Wave per node; 16 lanes per head stride the edge list; butterfly max-reduce.
// Exact: max_k leaky(el_k + ern) = leaky(max_k el_k + ern) by monotonicity.
__global__ __launch_bounds__(256) void k_emax(const float* __restrict__ el,
                                              const int* __restrict__ rowptr,
                                              const int* __restrict__ col,
                                              float* __restrict__ mx) {
    int wave = threadIdx.x >> 6, lane = threadIdx.x & 63;
    int n = blockIdx.x * 4 + wave;
    if (n >= N_NODES) return;
    int h = lane >> 4, sub = lane & 15;
    int r0 = rowptr[n], r1 = rowptr[n + 1];
    float m = -1e30f;
    for (int k = r0 + sub; k < r1; k += 16)
        m = fmaxf(m, el[col[k] * 4 + h]);
#pragma unroll
    for (int off = 8; off; off >>= 1)
        m = fmaxf(m, __shfl_xor(m, off));
    if (sub == 0) mx[n * 4 + h] = m;
}

// ---------------- GAT aggregation, D=64, single-pass (precomputed max), elu ----
// Wave per node: lane owns features [4*lane..4*lane+3] (8B fp16); head = lane>>4.
// Group-of-4 batched loads, order-preserving compute (no cross-edge serial chain).
__global__ __launch_bounds__(256) void gat_agg64(const __half* __restrict__ feat,
                                                 const float* __restrict__ el,
                                                 const float* __restrict__ er,
                                                 const float* __restrict__ mx,
                                                 const int* __restrict__ rowptr,
                                                 const int* __restrict__ col,
                                                 const float* __restrict__ bias,
                                                 const float* __restrict__ res,
                                                 float* __restrict__ out) {
    int wave = threadIdx.x >> 6, lane = threadIdx.x & 63;
    int n = blockIdx.x * 4 + wave;
    if (n >= N_NODES) return;
    int h = lane >> 4;
    int f0 = lane * 4;
    int r0 = rowptr[n], r1 = rowptr[n + 1];
    float ern = er[n * 4 + h];
    float M = mx[n * 4 + h] + ern;
    M = M > 0.f ? M : 0.2f * M;

    float denom = 0.f;
    float4 acc = make_float4(0.f, 0.f, 0.f, 0.f);

#define EDGE64(ev, uv)                                         \
    {                                                          \
        float e = (ev) + ern;                                  \
        e = e > 0.f ? e : 0.2f * e;                            \
        float p = __expf(e - M);                               \
        float2 flo = __half22float2(*(const __half2*)&(uv).x); \
        float2 fhi = __half22float2(*(const __half2*)&(uv).y); \
        denom += p;                                            \
        acc.x += p * flo.x;                                    \
        acc.y += p * flo.y;                                    \
        acc.z += p * fhi.x;                                    \
        acc.w += p * fhi.y;                                    \
    }

    int k = r0;
    for (; k + 4 <= r1; k += 4) {
        int s0 = col[k], s1 = col[k + 1], s2 = col[k + 2], s3 = col[k + 3];
        float ea = el[s0 * 4 + h], eb = el[s1 * 4 + h], ec = el[s2 * 4 + h], ed = el[s3 * 4 + h];
        uint2 ua = *(const uint2*)(feat + (size_t)s0 * 256 + f0);
        uint2 ub = *(const uint2*)(feat + (size_t)s1 * 256 + f0);
        uint2 uc = *(const uint2*)(feat + (size_t)s2 * 256 + f0);
        uint2 ud = *(const uint2*)(feat + (size_t)s3 * 256 + f0);
        EDGE64(ea, ua);
        EDGE64(eb, ub);
        EDGE64(ec, uc);
        EDGE64(ed, ud);
    }
    for (; k < r1; ++k) {
        int s = col[k];
        float ev = el[s * 4 + h];
        uint2 u = *(const uint2*)(feat + (size_t)s * 256 + f0);
        EDGE64(ev, u);
    }
#undef EDGE64

    float inv = 1.f / denom;
    float4 b4 = *(const float4*)(bias + f0);
    float4 o = make_float4(acc.x * inv + b4.x, acc.y * inv + b4.y,
                           acc.z * inv + b4.z, acc.w * inv + b4.w);
    if (res) {
        float4 rv = *(const float4*)(res + (size_t)n * 256 + f0);
        o.x += rv.x; o.y += rv.y; o.z += rv.z; o.w += rv.w;
    }
    o.x = o.x > 0.f ? o.x : __expf(o.x) - 1.f;
    o.y = o.y > 0.f ? o.y : __expf(o.y) - 1.f;
    o.z = o.z > 0.f ? o.z : __expf(o.z) - 1.f;
    o.w = o.w > 0.f ? o.w : __expf(o.w) - 1.f;
    *(float4*)(out + (size_t)n * 256 + f0) = o;
}

// ---------------- GAT aggregation, D=40 output layer, single-pass + head-mean --
// fp16 feat/res with row stride ld (layer-2 outputs in one fp16 [N][320] buffer).
__global__ __launch_bounds__(256) void gat_agg40(const __half* __restrict__ feat, int ld,
                                                 const float* __restrict__ el,
                                                 const float* __restrict__ er,
                                                 const float* __restrict__ mx,
                                                 const int* __restrict__ rowptr,
                                                 const int* __restrict__ col,
                                                 const float* __restrict__ bias,
                                                 const __half* __restrict__ res,
                                                 float* __restrict__ out) {
    int wave = threadIdx.x >> 6, lane = threadIdx.x & 63;
    int n = blockIdx.x * 4 + wave;
    if (n >= N_NODES) return;
    float4 o = make_float4(0.f, 0.f, 0.f, 0.f);
    if (lane < 40) {
        int h = lane / 10;
        int f0 = lane * 4;
        int r0 = rowptr[n], r1 = rowptr[n + 1];
        float ern = er[n * 4 + h];
        float M = mx[n * 4 + h] + ern;
        M = M > 0.f ? M : 0.2f * M;
        float denom = 0.f;
        float4 acc = make_float4(0.f, 0.f, 0.f, 0.f);

#define EDGE40(ev, uv)                                         \
    {                                                          \
        float e = (ev) + ern;                                  \
        e = e > 0.f ? e : 0.2f * e;                            \
        float p = __expf(e - M);                               \
        float2 flo = __half22float2(*(const __half2*)&(uv).x); \
        float2 fhi = __half22float2(*(const __half2*)&(uv).y); \
        denom += p;                                            \
        acc.x += p * flo.x;                                    \
        acc.y += p * flo.y;                                    \
        acc.z += p * fhi.x;                                    \
        acc.w += p * fhi.y;                                    \
    }

        int k = r0;
        for (; k + 4 <= r1; k += 4) {
            int s0 = col[k], s1 = col[k + 1], s2 = col[k + 2], s3 = col[k + 3];
            float ea = el[s0 * 4 + h], eb = el[s1 * 4 + h], ec = el[s2 * 4 + h], ed = el[s3 * 4 + h];
            uint2 ua = *(const uint2*)(feat + (size_t)s0 * ld + f0);
            uint2 ub = *(const uint2*)(feat + (size_t)s1 * ld + f0);
            uint2 uc = *(const uint2*)(feat + (size_t)s2 * ld + f0);
            uint2 ud = *(const uint2*)(feat + (size_t)s3 * ld + f0);
            EDGE40(ea, ua);
            EDGE40(eb, ub);
            EDGE40(ec, uc);
            EDGE40(ed, ud);
        }
        for (; k < r1; ++k) {
            int s = col[k];
            float ev = el[s * 4 + h];
            uint2 u = *(const uint2*)(feat + (size_t)s * ld + f0);
            EDGE40(ev, u);
        }
#undef EDGE40

        float inv = 1.f / denom;
        float4 b4 = *(const float4*)(bias + f0);
        uint2 ur = *(const uint2*)(res + (size_t)n * ld + f0);
        float2 rlo = __half22float2(*(const __half2*)&ur.x);
        float2 rhi = __half22float2(*(const __half2*)&ur.y);
        o = make_float4(acc.x * inv + b4.x + rlo.x, acc.y * inv + b4.y + rlo.y,
                        acc.z * inv + b4.z + rhi.x, acc.w * inv + b4.w + rhi.y);
    }
    float4 t;
    t.x = o.x + __shfl_down(o.x, 10) + __shfl_down(o.x, 20) + __shfl_down(o.x, 30);
    t.y = o.y + __shfl_down(o.y, 10) + __shfl_down(o.y, 20) + __shfl_down(o.y, 30);
    t.z = o.z + __shfl_down(o.z, 10) + __shfl_down(o.z, 20) + __shfl_down(o.z, 30);
    t.w = o.w + __shfl_down(o.w, 10) + __shfl_down(o.w, 20) + __shfl_down(o.w, 30);
    if (lane < 10) {
        float4 r4 = make_float4(0.25f * t.x, 0.25f * t.y, 0.25f * t.z, 0.25f * t.w);
        *(float4*)(out + (size_t)n * 40 + lane * 4) = r4;
    }
}

// ---------------- launch ----------------

extern "C" void kernel_launch(void* const* d_in, const int* in_sizes, int n_in,
                              void* d_out, int out_size, void* d_ws, size_t ws_size,
                              hipStream_t stream) {
    const float* x    = (const float*)d_in[0];
    const int* src    = (const int*)d_in[1];
    const int* dst    = (const int*)d_in[2];
    const float* W0   = (const float*)d_in[3];
    const float* al0  = (const float*)d_in[4];
    const float* ar0  = (const float*)d_in[5];
    const float* b0   = (const float*)d_in[6];
    const float* W1   = (const float*)d_in[7];
    const float* al1  = (const float*)d_in[8];
    const float* ar1  = (const float*)d_in[9];
    const float* b1   = (const float*)d_in[10];
    const float* W2   = (const float*)d_in[11];
    const float* al2  = (const float*)d_in[12];
    const float* ar2  = (const float*)d_in[13];
    const float* b2   = (const float*)d_in[14];
    const float* Wres2 = (const float*)d_in[15];
    float* out = (float*)d_out;

    char* ws = (char*)d_ws;
    auto alloc = [&](size_t bytes) {
        char* p = ws;
        ws += (bytes + 255) & ~(size_t)255;
        return p;
    };
    int* rowptr   = (int*)alloc((N_NODES + 1) * sizeof(int));
    int* cursor   = (int*)alloc(N_NODES * sizeof(int));
    int* cnt      = (int*)alloc(N_NODES * sizeof(int));
    int* bsum     = (int*)alloc(SCAN_BLOCKS * sizeof(int));
    int* bpre     = (int*)alloc(SCAN_BLOCKS * sizeof(int));
    int* colA     = (int*)alloc(N_EDGES * sizeof(int));
    float* el     = (float*)alloc((size_t)N_NODES * NH * sizeof(float));
    float* er     = (float*)alloc((size_t)N_NODES * NH * sizeof(float));
    float* mx     = (float*)alloc((size_t)N_NODES * NH * sizeof(float));
    float* bufB   = (float*)alloc((size_t)N_NODES * 256 * sizeof(float));   // h1
    float* bufC   = (float*)alloc((size_t)N_NODES * 256 * sizeof(float));   // h2
    __half* featH = (__half*)alloc((size_t)N_NODES * 256 * sizeof(__half)); // feat0/feat1
    __half* featH2= (__half*)alloc((size_t)N_NODES * 320 * sizeof(__half)); // [feat2|res2]
    short* W0hT   = (short*)alloc(256 * 256 * sizeof(short));
    short* W0lT   = (short*)alloc(256 * 256 * sizeof(short));
    short* W1hT   = (short*)alloc(256 * 256 * sizeof(short));
    short* W1lT   = (short*)alloc(256 * 256 * sizeof(short));
    short* WchT   = (short*)alloc(320 * 256 * sizeof(short));
    short* WclT   = (short*)alloc(320 * 256 * sizeof(short));

    // CSR by dst (shared across all 3 layers) — two-level parallel scan
    hipMemsetAsync(cnt, 0, N_NODES * sizeof(int), stream);
    k_hist<<<(N_EDGES + 255) / 256, 256, 0, stream>>>(dst, cnt, N_EDGES);
    k_bsum<<<SCAN_BLOCKS, 256, 0, stream>>>(cnt, bsum, N_NODES);
    k_bscan<<<1, 64, 0, stream>>>(bsum, bpre, SCAN_BLOCKS);
    k_scatter<<<SCAN_BLOCKS, 256, 0, stream>>>(cnt, bpre, rowptr, cursor, N_NODES);
    k_fill<<<(N_EDGES + 255) / 256, 256, 0, stream>>>(src, dst, cursor, colA, N_EDGES);

    // weight split+transpose (tiny)
    cvt_wT<<<(256 * 256 + 255) / 256, 256, 0, stream>>>(W0, W0hT, W0lT, 256, 256);
    cvt_wT<<<(256 * 256 + 255) / 256, 256, 0, stream>>>(W1, W1hT, W1lT, 256, 256);
    cvt_wT_cat<<<(320 * 256 + 255) / 256, 256, 0, stream>>>(W2, Wres2, WchT, WclT);

    dim3 g256(2, (N_NODES + 127) / 128);
    dim3 g320(3, (N_NODES + 127) / 128);
    int agg_grid = (N_NODES + 3) / 4;

    // layer 0: feat0 = x@W0 -> featH (fp16) ; h1 -> bufB (fp32)
    gemm_mfma<<<g256, 256, 0, stream>>>(x, W0hT, W0lT, featH, N_NODES, 256, 256);
    elr64<<<agg_grid, 256, 0, stream>>>(featH, al0, ar0, el, er, N_NODES);
    k_emax<<<agg_grid, 256, 0, stream>>>(el, rowptr, colA, mx);
    gat_agg64<<<agg_grid, 256, 0, stream>>>(featH, el, er, mx, rowptr, colA, b0, nullptr, bufB);

    // layer 1: feat1 = h1@W1 -> featH (feat0 dead) ; h2 -> bufC (res = bufB)
    gemm_mfma<<<g256, 256, 0, stream>>>(bufB, W1hT, W1lT, featH, N_NODES, 256, 256);
    elr64<<<agg_grid, 256, 0, stream>>>(featH, al1, ar1, el, er, N_NODES);
    k_emax<<<agg_grid, 256, 0, stream>>>(el, rowptr, colA, mx);
    gat_agg64<<<agg_grid, 256, 0, stream>>>(featH, el, er, mx, rowptr, colA, b1, bufB, bufC);

    // layer 2: [feat2 | res2] = h2 @ [W2 | Wres2] -> featH2 fp16 [N][320]
    gemm_mfma<<<g320, 256, 0, stream>>>(bufC, WchT, WclT, featH2, N_NODES, 320, 256);
    elr_gen<<<(N_NODES * NH + 255) / 256, 256, 0, stream>>>(featH2, 320, al2, ar2, el, er, N_NODES, NC);
    k_emax<<<agg_grid, 256, 0, stream>>>(el, rowptr, colA, mx);
    gat_agg40<<<agg_grid, 256, 0, stream>>>(featH2, 320, el, er, mx, rowptr, colA, b2, featH2 + 160, out);
}

// Round 13
// 586.607 us; speedup vs baseline: 1.8567x; 1.1050x over previous
//
#include <hip/hip_runtime.h>
#include <hip/hip_bf16.h>
#include <hip/hip_fp16.h>

#define N_NODES 50000
#define N_EDGES 800000
#define DIN 256
#define HID 64
#define NH 4
#define NC 40

typedef __attribute__((ext_vector_type(4))) short short4v;   // 8 B
typedef __attribute__((ext_vector_type(8))) short bf16x8;    // 16 B, MFMA A/B frag
typedef __attribute__((ext_vector_type(4))) float f32x4;     // 16 B, MFMA C/D frag

__device__ __forceinline__ unsigned short f2bf(float f) {
    unsigned u = __float_as_uint(f);
    unsigned r = (u + 0x7fffu + ((u >> 16) & 1u)) >> 16;  // RNE
    return (unsigned short)r;
}
__device__ __forceinline__ float bf2f(unsigned short b) {
    return __uint_as_float(((unsigned)b) << 16);
}

// ---------------- CSR build ----------------

__global__ void k_hist(const int* __restrict__ dst, int* __restrict__ cnt, int E) {
    int i = blockIdx.x * blockDim.x + threadIdx.x;
    if (i < E) atomicAdd(&cnt[dst[i]], 1);
}

// two-level parallel scan: 49 blocks x 1024 counts
#define SCAN_BLOCKS 49

__global__ __launch_bounds__(256) void k_bsum(const int* __restrict__ cnt,
                                              int* __restrict__ bsum, int Nn) {
    __shared__ int red[256];
    int b = blockIdx.x, t = threadIdx.x;
    int base = b * 1024 + t * 4;
    int s = 0;
    if (base + 3 < Nn) {
        int4 v = *(const int4*)(cnt + base);
        s = v.x + v.y + v.z + v.w;
    } else {
        for (int j = 0; j < 4; ++j)
            if (base + j < Nn) s += cnt[base + j];
    }
    red[t] = s;
    __syncthreads();
    for (int off = 128; off; off >>= 1) {
        if (t < off) red[t] += red[t + off];
        __syncthreads();
    }
    if (t == 0) bsum[b] = red[0];
}

__global__ void k_bscan(const int* __restrict__ bsum, int* __restrict__ bpre, int nb) {
    int l = threadIdx.x;  // single wave of 64
    int x = (l < nb) ? bsum[l] : 0;
    int v = x;
    for (int off = 1; off < 64; off <<= 1) {
        int u = __shfl_up(v, off);
        if (l >= off) v += u;
    }
    if (l < nb) bpre[l] = v - x;  // exclusive
}

__global__ __launch_bounds__(256) void k_scatter(const int* __restrict__ cnt,
                                                 const int* __restrict__ bpre,
                                                 int* __restrict__ rowptr,
                                                 int* __restrict__ cursor, int Nn) {
    __shared__ int red[256];
    int b = blockIdx.x, t = threadIdx.x;
    int base = b * 1024 + t * 4;
    int c[4];
    int s = 0;
    for (int j = 0; j < 4; ++j) {
        int idx = base + j;
        c[j] = (idx < Nn) ? cnt[idx] : 0;
        s += c[j];
    }
    red[t] = s;
    __syncthreads();
    for (int off = 1; off < 256; off <<= 1) {
        int v = (t >= off) ? red[t - off] : 0;
        __syncthreads();
        red[t] += v;
        __syncthreads();
    }
    int run = red[t] - s + bpre[b];  // exclusive prefix for this thread's 4 counts
    for (int j = 0; j < 4; ++j) {
        int idx = base + j;
        if (idx < Nn) {
            rowptr[idx] = run;
            cursor[idx] = run;
            run += c[j];
        }
    }
    if (b == 0 && t == 0) rowptr[Nn] = N_EDGES;  // every edge is histogrammed
}

__global__ void k_fill(const int* __restrict__ src, const int* __restrict__ dst,
                       int* __restrict__ cursor, int* __restrict__ col, int E) {
    int i = blockIdx.x * blockDim.x + threadIdx.x;
    if (i < E) {
        int p = atomicAdd(&cursor[dst[i]], 1);
        col[p] = src[i];
    }
}

// ---------------- weight convert: fp32 [K][NN] -> bf16 hi/lo transposed [NN][K] ----

__global__ void cvt_wT(const float* __restrict__ W, short* __restrict__ hT,
                       short* __restrict__ lT, int K, int NN) {
    int t = blockIdx.x * blockDim.x + threadIdx.x;
    if (t >= K * NN) return;
    int n = t / K, k = t - n * K;          // t = n*K + k -> coalesced writes
    float v = W[(size_t)k * NN + n];
    unsigned short h = f2bf(v);
    hT[t] = (short)h;
    lT[t] = (short)f2bf(v - bf2f(h));
}

// cat [W2 | Wres2] along N: NN=320, K=256
__global__ void cvt_wT_cat(const float* __restrict__ W2, const float* __restrict__ Wr,
                           short* __restrict__ hT, short* __restrict__ lT) {
    int t = blockIdx.x * blockDim.x + threadIdx.x;
    if (t >= 320 * 256) return;
    int n = t >> 8, k = t & 255;
    float v = (n < 160) ? W2[(size_t)k * 160 + n] : Wr[(size_t)k * 160 + (n - 160)];
    unsigned short h = f2bf(v);
    hT[t] = (short)h;
    lT[t] = (short)f2bf(v - bf2f(h));
}

// ---------------- bf16x3-split MFMA GEMM, fp16 output, reg-staged dbuf ----------
// C[M][NN] (fp16) = A[M][K] (fp32) @ B[K][NN], B pre-split+transposed bf16 [NN][K].
// BM=BN=128, BK=32, 256 threads (4 waves), wave = 64x64 via 4x4 frags of 16x16x32.
// A ~ Ah+Al, B ~ Bh+Bl; acc += AhBh + AhBl + AlBh (fp32 accum).
// T14 async-STAGE: next tile's global loads issue BEFORE this tile's MFMA;
// their vmcnt waits sink into write_lds after the MFMA -> latency hidden.

#define SK 40  // LDS k-stride in shorts (32 + 8 pad; 80B row stride = 16B-aligned, 2-way banks)

__global__ __launch_bounds__(256) void gemm_mfma(const float* __restrict__ A,
                                                 const short* __restrict__ BhT,
                                                 const short* __restrict__ BlT,
                                                 __half* __restrict__ C,
                                                 int M, int NN, int K) {
    __shared__ short Ah[128 * SK], Al[128 * SK], Bh[128 * SK], Bl[128 * SK];
    const int tid = threadIdx.x;
    const int bm = blockIdx.y * 128;
    const int bn = blockIdx.x * 128;
    const int w = tid >> 6, l = tid & 63;
    const int wr = w >> 1, wc = w & 1;      // wave tile (row, col) in 2x2
    const int rowf = l & 15, kg = l >> 4;   // fragment row, k-group

    f32x4 acc[4][4] = {};
    f32x4 va[4];   // prefetched A chunks (fp32)
    bf16x8 vb[4];  // prefetched B chunks (pre-split bf16)

    // thread -> staging coordinates (constant across iters)
    const int a_row = tid >> 3;              // with it*32 added per chunk
    // chunk = tid + it*256: row = chunk>>3, kc = chunk&7
    // B: tile = chunk>>9, nrow = (chunk&511)>>2, kc = chunk&3

    auto load_regs = [&](int k0) {
#pragma unroll
        for (int it = 0; it < 4; ++it) {
            int chunk = tid + it * 256;
            int row = chunk >> 3, kc = chunk & 7;
            va[it] = f32x4{};
            int ar = bm + row;
            if (ar < M) va[it] = *(const f32x4*)(A + (size_t)ar * K + k0 + kc * 4);
        }
#pragma unroll
        for (int it = 0; it < 4; ++it) {
            int chunk = tid + it * 256;
            int tile = chunk >> 9, c2 = chunk & 511;
            int nrow = c2 >> 2, kc = c2 & 3;
            vb[it] = bf16x8{};
            int gn = bn + nrow;
            const short* srcT = tile ? BlT : BhT;
            if (gn < NN) vb[it] = *(const bf16x8*)(srcT + (size_t)gn * K + k0 + kc * 8);
        }
    };

    auto write_lds = [&]() {
#pragma unroll
        for (int it = 0; it < 4; ++it) {
            int chunk = tid + it * 256;
            int row = chunk >> 3, kc = chunk & 7;
            short4v hi, lo;
#pragma unroll
            for (int j = 0; j < 4; ++j) {
                unsigned short h_ = f2bf(va[it][j]);
                hi[j] = (short)h_;
                lo[j] = (short)f2bf(va[it][j] - bf2f(h_));
            }
            *(short4v*)&Ah[row * SK + kc * 4] = hi;
            *(short4v*)&Al[row * SK + kc * 4] = lo;
        }
#pragma unroll
        for (int it = 0; it < 4; ++it) {
            int chunk = tid + it * 256;
            int tile = chunk >> 9, c2 = chunk & 511;
            int nrow = c2 >> 2, kc = c2 & 3;
            short* dstT = tile ? Bl : Bh;
            *(bf16x8*)&dstT[nrow * SK + kc * 8] = vb[it];
        }
    };

    auto do_mfma = [&]() {
        bf16x8 afh[4], afl[4], bfh[4], bfl[4];
#pragma unroll
        for (int m = 0; m < 4; ++m) {
            int off = (wr * 64 + m * 16 + rowf) * SK + kg * 8;
            afh[m] = *(const bf16x8*)&Ah[off];
            afl[m] = *(const bf16x8*)&Al[off];
        }
#pragma unroll
        for (int n = 0; n < 4; ++n) {
            int off = (wc * 64 + n * 16 + rowf) * SK + kg * 8;
            bfh[n] = *(const bf16x8*)&Bh[off];
            bfl[n] = *(const bf16x8*)&Bl[off];
        }
#pragma unroll
        for (int m = 0; m < 4; ++m)
#pragma unroll
            for (int n = 0; n < 4; ++n) {
                acc[m][n] = __builtin_amdgcn_mfma_f32_16x16x32_bf16(afh[m], bfh[n], acc[m][n], 0, 0, 0);
                acc[m][n] = __builtin_amdgcn_mfma_f32_16x16x32_bf16(afh[m], bfl[n], acc[m][n], 0, 0, 0);
                acc[m][n] = __builtin_amdgcn_mfma_f32_16x16x32_bf16(afl[m], bfh[n], acc[m][n], 0, 0, 0);
            }
    };

    // prologue: tile 0 into LDS
    load_regs(0);
    write_lds();
    __syncthreads();

    for (int k0 = 32; k0 < K; k0 += 32) {
        load_regs(k0);   // issue next tile's global loads (consumed in write_lds)
        do_mfma();       // compute on current LDS tile, hides load latency
        __syncthreads(); // all frag reads done
        write_lds();     // vmcnt waits land here, after MFMA
        __syncthreads(); // next tile ready
    }
    do_mfma();           // last tile

    // ---- epilogue: D[row=(l>>4)*4+r][col=l&15] (guide-verified layout), fp16 store
#pragma unroll
    for (int m = 0; m < 4; ++m)
#pragma unroll
        for (int r = 0; r < 4; ++r) {
            int grow = bm + wr * 64 + m * 16 + kg * 4 + r;
            if (grow >= M) continue;
#pragma unroll
            for (int n = 0; n < 4; ++n) {
                int gcol = bn + wc * 64 + n * 16 + rowf;
                if (gcol < NN) C[(size_t)grow * NN + gcol] = __float2half(acc[m][n][r]);
            }
        }
}

// ---------------- el/er projections (fp16 feat, vectorized) ----------------
// Wave per node; 16 lanes per head; lane reads 4 contiguous halves (uint2).
__global__ __launch_bounds__(256) void elr64(const __half* __restrict__ feat,
                                             const float* __restrict__ al,
                                             const float* __restrict__ ar,
                                             float* __restrict__ el,
                                             float* __restrict__ er, int Nn) {
    int wave = threadIdx.x >> 6, lane = threadIdx.x & 63;
    int n = blockIdx.x * 4 + wave;
    if (n >= Nn) return;
    int g = lane >> 4;            // head
    int i4 = (lane & 15) * 4;     // element offset within head
    int off = g * 64 + i4;
    uint2 u = *(const uint2*)(feat + (size_t)n * 256 + off);
    float4 a4 = *(const float4*)(al + off);
    float4 r4 = *(const float4*)(ar + off);
    float2 lo = __half22float2(*(const __half2*)&u.x);
    float2 hi = __half22float2(*(const __half2*)&u.y);
    float sl = lo.x * a4.x + lo.y * a4.y + hi.x * a4.z + hi.y * a4.w;
    float sr = lo.x * r4.x + lo.y * r4.y + hi.x * r4.z + hi.y * r4.w;
#pragma unroll
    for (int o = 8; o; o >>= 1) {
        sl += __shfl_down(sl, o);
        sr += __shfl_down(sr, o);
    }
    if ((lane & 15) == 0) {
        el[n * 4 + g] = sl;
        er[n * 4 + g] = sr;
    }
}

// D=40 output layer: one thread per (n,h); fp16 feat with row stride ld
__global__ void elr_gen(const __half* __restrict__ feat, int ld,
                        const float* __restrict__ al, const float* __restrict__ ar,
                        float* __restrict__ el, float* __restrict__ er, int Nn, int D) {
    int i = blockIdx.x * blockDim.x + threadIdx.x;
    if (i >= Nn * NH) return;
    int n = i / NH, h = i % NH;
    const __half* f = feat + (size_t)n * ld + h * D;
    const float* a = al + h * D;
    const float* r = ar + h * D;
    float sl = 0.f, sr = 0.f;
#pragma unroll
    for (int q = 0; q < 10; ++q) {  // D=40 = 10 x uint2
        uint2 u = *(const uint2*)(f + q * 4);
        float2 lo = __half22float2(*(const __half2*)&u.x);
        float2 hi = __half22float2(*(const __half2*)&u.y);
        sl += lo.x * a[q * 4] + lo.y * a[q * 4 + 1] + hi.x * a[q * 4 + 2] + hi.y * a[q * 4 + 3];
        sr += lo.x * r[q * 4] + lo.y * r[q * 4 + 1] + hi.x * r[q * 4 + 2] + hi.y * r[q * 4 + 3];
    }
    el[i] = sl;
    er[i] = sr;
}

// ---------------- per-(node,head) max of el over in-neighbors ----------------
// Wave per node; 16 lanes per head stride the edge list; butterfly max-reduce.
// Exact: max_k leaky(el_k + ern) = leaky(max_k el_k + ern) by monotonicity.
__global__ __launch_bounds__(256) void k_emax(const float* __restrict__ el,
                                              const int* __restrict__ rowptr,
                                              const int* __restrict__ col,
                                              float* __restrict__ mx) {
    int wave = threadIdx.x >> 6, lane = threadIdx.x & 63;
    int n = blockIdx.x * 4 + wave;
    if (n >= N_NODES) return;
    int h = lane >> 4, sub = lane & 15;
    int r0 = rowptr[n], r1 = rowptr[n + 1];
    float m = -1e30f;
    for (int k = r0 + sub; k < r1; k += 16)
        m = fmaxf(m, el[col[k] * 4 + h]);
#pragma unroll
    for (int off = 8; off; off >>= 1)
        m = fmaxf(m, __shfl_xor(m, off));
    if (sub == 0) mx[n * 4 + h] = m;
}

// ---------------- GAT aggregation, D=64, single-pass (precomputed max), elu ----
// Wave per node: lane owns features [4*lane..4*lane+3] (8B fp16); head = lane>>4.
// Group-of-4 batched loads, order-preserving compute (no cross-edge serial chain).
__global__ __launch_bounds__(256) void gat_agg64(const __half* __restrict__ feat,
                                                 const float* __restrict__ el,
                                                 const float* __restrict__ er,
                                                 const float* __restrict__ mx,
                                                 const int* __restrict__ rowptr,
                                                 const int* __restrict__ col,
                                                 const float* __restrict__ bias,
                                                 const float* __restrict__ res,
                                                 float* __restrict__ out) {
    int wave = threadIdx.x >> 6, lane = threadIdx.x & 63;
    int n = blockIdx.x * 4 + wave;
    if (n >= N_NODES) return;
    int h = lane >> 4;
    int f0 = lane * 4;
    int r0 = rowptr[n], r1 = rowptr[n + 1];
    float ern = er[n * 4 + h];
    float M = mx[n * 4 + h] + ern;
    M = M > 0.f ? M : 0.2f * M;

    float denom = 0.f;
    float4 acc = make_float4(0.f, 0.f, 0.f, 0.f);

#define EDGE64(ev, uv)                                         \
    {                                                          \
        float e = (ev) + ern;                                  \
        e = e > 0.f ? e : 0.2f * e;                            \
        float p = __expf(e - M);                               \
        float2 flo = __half22float2(*(const __half2*)&(uv).x); \
        float2 fhi = __half22float2(*(const __half2*)&(uv).y); \
        denom += p;                                            \
        acc.x += p * flo.x;                                    \
        acc.y += p * flo.y;                                    \
        acc.z += p * fhi.x;                                    \
        acc.w += p * fhi.y;                                    \
    }

    int k = r0;
    for (; k + 4 <= r1; k += 4) {
        int s0 = col[k], s1 = col[k + 1], s2 = col[k + 2], s3 = col[k + 3];
        float ea = el[s0 * 4 + h], eb = el[s1 * 4 + h], ec = el[s2 * 4 + h], ed = el[s3 * 4 + h];
        uint2 ua = *(const uint2*)(feat + (size_t)s0 * 256 + f0);
        uint2 ub = *(const uint2*)(feat + (size_t)s1 * 256 + f0);
        uint2 uc = *(const uint2*)(feat + (size_t)s2 * 256 + f0);
        uint2 ud = *(const uint2*)(feat + (size_t)s3 * 256 + f0);
        EDGE64(ea, ua);
        EDGE64(eb, ub);
        EDGE64(ec, uc);
        EDGE64(ed, ud);
    }
    for (; k < r1; ++k) {
        int s = col[k];
        float ev = el[s * 4 + h];
        uint2 u = *(const uint2*)(feat + (size_t)s * 256 + f0);
        EDGE64(ev, u);
    }
#undef EDGE64

    float inv = 1.f / denom;
    float4 b4 = *(const float4*)(bias + f0);
    float4 o = make_float4(acc.x * inv + b4.x, acc.y * inv + b4.y,
                           acc.z * inv + b4.z, acc.w * inv + b4.w);
    if (res) {
        float4 rv = *(const float4*)(res + (size_t)n * 256 + f0);
        o.x += rv.x; o.y += rv.y; o.z += rv.z; o.w += rv.w;
    }
    o.x = o.x > 0.f ? o.x : __expf(o.x) - 1.f;
    o.y = o.y > 0.f ? o.y : __expf(o.y) - 1.f;
    o.z = o.z > 0.f ? o.z : __expf(o.z) - 1.f;
    o.w = o.w > 0.f ? o.w : __expf(o.w) - 1.f;
    *(float4*)(out + (size_t)n * 256 + f0) = o;
}

// ---------------- GAT aggregation, D=40 output layer, single-pass + head-mean --
// fp16 feat/res with row stride ld (layer-2 outputs in one fp16 [N][320] buffer).
__global__ __launch_bounds__(256) void gat_agg40(const __half* __restrict__ feat, int ld,
                                                 const float* __restrict__ el,
                                                 const float* __restrict__ er,
                                                 const float* __restrict__ mx,
                                                 const int* __restrict__ rowptr,
                                                 const int* __restrict__ col,
                                                 const float* __restrict__ bias,
                                                 const __half* __restrict__ res,
                                                 float* __restrict__ out) {
    int wave = threadIdx.x >> 6, lane = threadIdx.x & 63;
    int n = blockIdx.x * 4 + wave;
    if (n >= N_NODES) return;
    float4 o = make_float4(0.f, 0.f, 0.f, 0.f);
    if (lane < 40) {
        int h = lane / 10;
        int f0 = lane * 4;
        int r0 = rowptr[n], r1 = rowptr[n + 1];
        float ern = er[n * 4 + h];
        float M = mx[n * 4 + h] + ern;
        M = M > 0.f ? M : 0.2f * M;
        float denom = 0.f;
        float4 acc = make_float4(0.f, 0.f, 0.f, 0.f);

#define EDGE40(ev, uv)                                         \
    {                                                          \
        float e = (ev) + ern;                                  \
        e = e > 0.f ? e : 0.2f * e;                            \
        float p = __expf(e - M);                               \
        float2 flo = __half22float2(*(const __half2*)&(uv).x); \
        float2 fhi = __half22float2(*(const __half2*)&(uv).y); \
        denom += p;                                            \
        acc.x += p * flo.x;                                    \
        acc.y += p * flo.y;                                    \
        acc.z += p * fhi.x;                                    \
        acc.w += p * fhi.y;                                    \
    }

        int k = r0;
        for (; k + 4 <= r1; k += 4) {
            int s0 = col[k], s1 = col[k + 1], s2 = col[k + 2], s3 = col[k + 3];
            float ea = el[s0 * 4 + h], eb = el[s1 * 4 + h], ec = el[s2 * 4 + h], ed = el[s3 * 4 + h];
            uint2 ua = *(const uint2*)(feat + (size_t)s0 * ld + f0);
            uint2 ub = *(const uint2*)(feat + (size_t)s1 * ld + f0);
            uint2 uc = *(const uint2*)(feat + (size_t)s2 * ld + f0);
            uint2 ud = *(const uint2*)(feat + (size_t)s3 * ld + f0);
            EDGE40(ea, ua);
            EDGE40(eb, ub);
            EDGE40(ec, uc);
            EDGE40(ed, ud);
        }
        for (; k < r1; ++k) {
            int s = col[k];
            float ev = el[s * 4 + h];
            uint2 u = *(const uint2*)(feat + (size_t)s * ld + f0);
            EDGE40(ev, u);
        }
#undef EDGE40

        float inv = 1.f / denom;
        float4 b4 = *(const float4*)(bias + f0);
        uint2 ur = *(const uint2*)(res + (size_t)n * ld + f0);
        float2 rlo = __half22float2(*(const __half2*)&ur.x);
        float2 rhi = __half22float2(*(const __half2*)&ur.y);
        o = make_float4(acc.x * inv + b4.x + rlo.x, acc.y * inv + b4.y + rlo.y,
                        acc.z * inv + b4.z + rhi.x, acc.w * inv + b4.w + rhi.y);
    }
    float4 t;
    t.x = o.x + __shfl_down(o.x, 10) + __shfl_down(o.x, 20) + __shfl_down(o.x, 30);
    t.y = o.y + __shfl_down(o.y, 10) + __shfl_down(o.y, 20) + __shfl_down(o.y, 30);
    t.z = o.z + __shfl_down(o.z, 10) + __shfl_down(o.z, 20) + __shfl_down(o.z, 30);
    t.w = o.w + __shfl_down(o.w, 10) + __shfl_down(o.w, 20) + __shfl_down(o.w, 30);
    if (lane < 10) {
        float4 r4 = make_float4(0.25f * t.x, 0.25f * t.y, 0.25f * t.z, 0.25f * t.w);
        *(float4*)(out + (size_t)n * 40 + lane * 4) = r4;
    }
}

// ---------------- launch ----------------

extern "C" void kernel_launch(void* const* d_in, const int* in_sizes, int n_in,
                              void* d_out, int out_size, void* d_ws, size_t ws_size,
                              hipStream_t stream) {
    const float* x    = (const float*)d_in[0];
    const int* src    = (const int*)d_in[1];
    const int* dst    = (const int*)d_in[2];
    const float* W0   = (const float*)d_in[3];
    const float* al0  = (const float*)d_in[4];
    const float* ar0  = (const float*)d_in[5];
    const float* b0   = (const float*)d_in[6];
    const float* W1   = (const float*)d_in[7];
    const float* al1  = (const float*)d_in[8];
    const float* ar1  = (const float*)d_in[9];
    const float* b1   = (const float*)d_in[10];
    const float* W2   = (const float*)d_in[11];
    const float* al2  = (const float*)d_in[12];
    const float* ar2  = (const float*)d_in[13];
    const float* b2   = (const float*)d_in[14];
    const float* Wres2 = (const float*)d_in[15];
    float* out = (float*)d_out;

    char* ws = (char*)d_ws;
    auto alloc = [&](size_t bytes) {
        char* p = ws;
        ws += (bytes + 255) & ~(size_t)255;
        return p;
    };
    int* rowptr   = (int*)alloc((N_NODES + 1) * sizeof(int));
    int* cursor   = (int*)alloc(N_NODES * sizeof(int));
    int* cnt      = (int*)alloc(N_NODES * sizeof(int));
    int* bsum     = (int*)alloc(SCAN_BLOCKS * sizeof(int));
    int* bpre     = (int*)alloc(SCAN_BLOCKS * sizeof(int));
    int* colA     = (int*)alloc(N_EDGES * sizeof(int));
    float* el     = (float*)alloc((size_t)N_NODES * NH * sizeof(float));
    float* er     = (float*)alloc((size_t)N_NODES * NH * sizeof(float));
    float* mx     = (float*)alloc((size_t)N_NODES * NH * sizeof(float));
    float* bufB   = (float*)alloc((size_t)N_NODES * 256 * sizeof(float));   // h1
    float* bufC   = (float*)alloc((size_t)N_NODES * 256 * sizeof(float));   // h2
    __half* featH = (__half*)alloc((size_t)N_NODES * 256 * sizeof(__half)); // feat0/feat1
    __half* featH2= (__half*)alloc((size_t)N_NODES * 320 * sizeof(__half)); // [feat2|res2]
    short* W0hT   = (short*)alloc(256 * 256 * sizeof(short));
    short* W0lT   = (short*)alloc(256 * 256 * sizeof(short));
    short* W1hT   = (short*)alloc(256 * 256 * sizeof(short));
    short* W1lT   = (short*)alloc(256 * 256 * sizeof(short));
    short* WchT   = (short*)alloc(320 * 256 * sizeof(short));
    short* WclT   = (short*)alloc(320 * 256 * sizeof(short));

    // CSR by dst (shared across all 3 layers) — two-level parallel scan
    hipMemsetAsync(cnt, 0, N_NODES * sizeof(int), stream);
    k_hist<<<(N_EDGES + 255) / 256, 256, 0, stream>>>(dst, cnt, N_EDGES);
    k_bsum<<<SCAN_BLOCKS, 256, 0, stream>>>(cnt, bsum, N_NODES);
    k_bscan<<<1, 64, 0, stream>>>(bsum, bpre, SCAN_BLOCKS);
    k_scatter<<<SCAN_BLOCKS, 256, 0, stream>>>(cnt, bpre, rowptr, cursor, N_NODES);
    k_fill<<<(N_EDGES + 255) / 256, 256, 0, stream>>>(src, dst, cursor, colA, N_EDGES);

    // weight split+transpose (tiny)
    cvt_wT<<<(256 * 256 + 255) / 256, 256, 0, stream>>>(W0, W0hT, W0lT, 256, 256);
    cvt_wT<<<(256 * 256 + 255) / 256, 256, 0, stream>>>(W1, W1hT, W1lT, 256, 256);
    cvt_wT_cat<<<(320 * 256 + 255) / 256, 256, 0, stream>>>(W2, Wres2, WchT, WclT);

    dim3 g256(2, (N_NODES + 127) / 128);
    dim3 g320(3, (N_NODES + 127) / 128);
    int agg_grid = (N_NODES + 3) / 4;

    // layer 0: feat0 = x@W0 -> featH (fp16) ; h1 -> bufB (fp32)
    gemm_mfma<<<g256, 256, 0, stream>>>(x, W0hT, W0lT, featH, N_NODES, 256, 256);
    elr64<<<agg_grid, 256, 0, stream>>>(featH, al0, ar0, el, er, N_NODES);
    k_emax<<<agg_grid, 256, 0, stream>>>(el, rowptr, colA, mx);
    gat_agg64<<<agg_grid, 256, 0, stream>>>(featH, el, er, mx, rowptr, colA, b0, nullptr, bufB);

    // layer 1: feat1 = h1@W1 -> featH (feat0 dead) ; h2 -> bufC (res = bufB)
    gemm_mfma<<<g256, 256, 0, stream>>>(bufB, W1hT, W1lT, featH, N_NODES, 256, 256);
    elr64<<<agg_grid, 256, 0, stream>>>(featH, al1, ar1, el, er, N_NODES);
    k_emax<<<agg_grid, 256, 0, stream>>>(el, rowptr, colA, mx);
    gat_agg64<<<agg_grid, 256, 0, stream>>>(featH, el, er, mx, rowptr, colA, b1, bufB, bufC);

    // layer 2: [feat2 | res2] = h2 @ [W2 | Wres2] -> featH2 fp16 [N][320]
    gemm_mfma<<<g320, 256, 0, stream>>>(bufC, WchT, WclT, featH2, N_NODES, 320, 256);
    elr_gen<<<(N_NODES * NH + 255) / 256, 256, 0, stream>>>(featH2, 320, al2, ar2, el, er, N_NODES, NC);
    k_emax<<<agg_grid, 256, 0, stream>>>(el, rowptr, colA, mx);
    gat_agg40<<<agg_grid, 256, 0, stream>>>(featH2, 320, el, er, mx, rowptr, colA, b2, featH2 + 160, out);
}